// Round 1
// baseline (5835.651 us; speedup 1.0000x reference)
//
#include <hip/hip_runtime.h>

#define NN 20000
#define NE 320000
#define FIN 64
#define HD 256
#define NC 10
#define NG 64

// ---------------- init: deg=1, pool=0, cnt=0 ----------------
__global__ void k_init(float* __restrict__ deg, float* __restrict__ pool, float* __restrict__ cnt) {
    int i = blockIdx.x * 256 + threadIdx.x;
    if (i < NN) deg[i] = 1.0f;
    if (i < NG * HD) pool[i] = 0.0f;
    if (i < NG) cnt[i] = 0.0f;
}

// ---------------- degree count over edge targets ----------------
__global__ void k_degcount(const int* __restrict__ col, float* __restrict__ deg) {
    int i = blockIdx.x * 256 + threadIdx.x;
    if (i < NE) atomicAdd(&deg[col[i]], 1.0f);
}

__global__ void k_dinv(float* __restrict__ deg) {
    int i = blockIdx.x * 256 + threadIdx.x;
    if (i < NN) deg[i] = rsqrtf(deg[i]);
}

// ---------------- fp32 tiled matmul: Ys = (A @ W) * dinv[row]; S = Ys ------
// A: [NN, K] row-major, W: [K, 256] row-major. Tile 64x64, BK=16.
__global__ __launch_bounds__(256) void k_matmul(const float* __restrict__ A,
                                                const float* __restrict__ W,
                                                const float* __restrict__ dinv,
                                                float* __restrict__ Y,
                                                float* __restrict__ S,
                                                int K) {
    __shared__ float As[16][64];
    __shared__ float Ws[16][64];
    const int m0 = blockIdx.x * 64;
    const int n0 = blockIdx.y * 64;
    const int t = threadIdx.x;
    const int tm = (t >> 4) << 2;   // 0..60
    const int tn = (t & 15) << 2;   // 0..60
    float acc[4][4] = {};

    const int la_m = t >> 2;          // 0..63
    const int la_k = (t & 3) << 2;    // 0,4,8,12
    const int lw_k = t >> 4;          // 0..15
    const int lw_n = (t & 15) << 2;   // 0..60

    for (int k0 = 0; k0 < K; k0 += 16) {
        float4 av;
        int gm = m0 + la_m;
        if (gm < NN) av = *(const float4*)&A[(size_t)gm * K + k0 + la_k];
        else av = make_float4(0.f, 0.f, 0.f, 0.f);
        As[la_k + 0][la_m] = av.x;
        As[la_k + 1][la_m] = av.y;
        As[la_k + 2][la_m] = av.z;
        As[la_k + 3][la_m] = av.w;
        *(float4*)&Ws[lw_k][lw_n] = *(const float4*)&W[(size_t)(k0 + lw_k) * HD + n0 + lw_n];
        __syncthreads();
#pragma unroll
        for (int k = 0; k < 16; ++k) {
            float4 a = *(const float4*)&As[k][tm];
            float4 w = *(const float4*)&Ws[k][tn];
            acc[0][0] = fmaf(a.x, w.x, acc[0][0]); acc[0][1] = fmaf(a.x, w.y, acc[0][1]);
            acc[0][2] = fmaf(a.x, w.z, acc[0][2]); acc[0][3] = fmaf(a.x, w.w, acc[0][3]);
            acc[1][0] = fmaf(a.y, w.x, acc[1][0]); acc[1][1] = fmaf(a.y, w.y, acc[1][1]);
            acc[1][2] = fmaf(a.y, w.z, acc[1][2]); acc[1][3] = fmaf(a.y, w.w, acc[1][3]);
            acc[2][0] = fmaf(a.z, w.x, acc[2][0]); acc[2][1] = fmaf(a.z, w.y, acc[2][1]);
            acc[2][2] = fmaf(a.z, w.z, acc[2][2]); acc[2][3] = fmaf(a.z, w.w, acc[2][3]);
            acc[3][0] = fmaf(a.w, w.x, acc[3][0]); acc[3][1] = fmaf(a.w, w.y, acc[3][1]);
            acc[3][2] = fmaf(a.w, w.z, acc[3][2]); acc[3][3] = fmaf(a.w, w.w, acc[3][3]);
        }
        __syncthreads();
    }
#pragma unroll
    for (int i = 0; i < 4; ++i) {
        int gm = m0 + tm + i;
        if (gm >= NN) break;
        float d = dinv[gm];
        float4 v = make_float4(acc[i][0] * d, acc[i][1] * d, acc[i][2] * d, acc[i][3] * d);
        *(float4*)&Y[(size_t)gm * HD + n0 + tn] = v;
        *(float4*)&S[(size_t)gm * HD + n0 + tn] = v;
    }
}

// ---------------- edge scatter: S[col] += Ys[row], one wave per edge -------
__global__ __launch_bounds__(256) void k_scatter(const float* __restrict__ Y,
                                                 float* __restrict__ S,
                                                 const int* __restrict__ row,
                                                 const int* __restrict__ col) {
    int w = blockIdx.x * 4 + (threadIdx.x >> 6);
    int lane = threadIdx.x & 63;
    if (w >= NE) return;
    int r = row[w], c = col[w];
    const float4 v = *(const float4*)&Y[(size_t)r * HD + lane * 4];
    float* dst = &S[(size_t)c * HD + lane * 4];
    atomicAdd(dst + 0, v.x);
    atomicAdd(dst + 1, v.y);
    atomicAdd(dst + 2, v.z);
    atomicAdd(dst + 3, v.w);
}

// ---------------- h = relu(dinv[i]*S + b) ----------------
__global__ void k_bias_relu(const float* __restrict__ S, const float* __restrict__ dinv,
                            const float* __restrict__ b, float* __restrict__ h) {
    int idx = blockIdx.x * 256 + threadIdx.x;   // one float4 per thread
    if (idx >= NN * (HD / 4)) return;
    int node = idx >> 6;        // /64
    int f4 = idx & 63;
    float d = dinv[node];
    float4 s = *(const float4*)&S[(size_t)idx * 4];
    float4 bb = *(const float4*)&b[f4 * 4];
    float4 r;
    r.x = fmaxf(fmaf(s.x, d, bb.x), 0.f);
    r.y = fmaxf(fmaf(s.y, d, bb.y), 0.f);
    r.z = fmaxf(fmaf(s.z, d, bb.z), 0.f);
    r.w = fmaxf(fmaf(s.w, d, bb.w), 0.f);
    *(float4*)&h[(size_t)idx * 4] = r;
}

// ---------------- pooling: pool[g] += h[n], cnt[g] += 1; one wave per node -
__global__ __launch_bounds__(256) void k_poolsum(const float* __restrict__ h,
                                                 const int* __restrict__ batch,
                                                 float* __restrict__ pool,
                                                 float* __restrict__ cnt) {
    int n = blockIdx.x * 4 + (threadIdx.x >> 6);
    int lane = threadIdx.x & 63;
    if (n >= NN) return;
    int g = batch[n];
    const float4 v = *(const float4*)&h[(size_t)n * HD + lane * 4];
    float* dst = &pool[(size_t)g * HD + lane * 4];
    atomicAdd(dst + 0, v.x);
    atomicAdd(dst + 1, v.y);
    atomicAdd(dst + 2, v.z);
    atomicAdd(dst + 3, v.w);
    if (lane == 0) atomicAdd(&cnt[g], 1.0f);
}

// ---------------- head: out[g][c] = (pool[g]/cnt[g]) . Wout[:,c] + bout[c] -
__global__ __launch_bounds__(64) void k_out(const float* __restrict__ pool,
                                            const float* __restrict__ cnt,
                                            const float* __restrict__ Wout,
                                            const float* __restrict__ bout,
                                            float* __restrict__ out) {
    int b = blockIdx.x;       // 0..639
    int g = b / NC;
    int c = b % NC;
    int lane = threadIdx.x;
    float s = 0.f;
#pragma unroll
    for (int j = 0; j < 4; ++j) {
        int f = lane * 4 + j;
        s = fmaf(pool[(size_t)g * HD + f], Wout[(size_t)f * NC + c], s);
    }
#pragma unroll
    for (int off = 32; off > 0; off >>= 1) s += __shfl_down(s, off);
    if (lane == 0) {
        float inv = 1.0f / fmaxf(cnt[g], 1.0f);
        out[(size_t)g * NC + c] = fmaf(s, inv, bout[c]);
    }
}

extern "C" void kernel_launch(void* const* d_in, const int* in_sizes, int n_in,
                              void* d_out, int out_size, void* d_ws, size_t ws_size,
                              hipStream_t stream) {
    const float* x     = (const float*)d_in[0];
    const int*   ei    = (const int*)d_in[1];
    const int*   batch = (const int*)d_in[2];
    const float* Wl[5] = {(const float*)d_in[3], (const float*)d_in[5], (const float*)d_in[7],
                          (const float*)d_in[9], (const float*)d_in[11]};
    const float* bl[5] = {(const float*)d_in[4], (const float*)d_in[6], (const float*)d_in[8],
                          (const float*)d_in[10], (const float*)d_in[12]};
    const float* Wout = (const float*)d_in[13];
    const float* bout = (const float*)d_in[14];
    float* out = (float*)d_out;

    const int* row = ei;
    const int* col = ei + NE;

    float* dinv = (float*)d_ws;                               // NN floats
    float* Y    = (float*)((char*)d_ws + 81920);              // NN*HD
    float* S    = Y + (size_t)NN * HD;                        // NN*HD
    float* h    = S + (size_t)NN * HD;                        // NN*HD
    float* pool = h + (size_t)NN * HD;                        // NG*HD
    float* cnt  = pool + (size_t)NG * HD;                     // NG

    // degrees + init
    k_init<<<(NN + 255) / 256, 256, 0, stream>>>(dinv, pool, cnt);
    k_degcount<<<(NE + 255) / 256, 256, 0, stream>>>(col, dinv);
    k_dinv<<<(NN + 255) / 256, 256, 0, stream>>>(dinv);

    dim3 mmGrid((NN + 63) / 64, HD / 64);
    const float* Ain = x;
    int K = FIN;
    for (int l = 0; l < 5; ++l) {
        k_matmul<<<mmGrid, 256, 0, stream>>>(Ain, Wl[l], dinv, Y, S, K);
        k_scatter<<<(NE + 3) / 4, 256, 0, stream>>>(Y, S, row, col);
        k_bias_relu<<<(NN * (HD / 4) + 255) / 256, 256, 0, stream>>>(S, dinv, bl[l], h);
        Ain = h;
        K = HD;
    }

    k_poolsum<<<(NN + 3) / 4, 256, 0, stream>>>(h, batch, pool, cnt);
    k_out<<<NG * NC, 64, 0, stream>>>(pool, cnt, Wout, bout, out);
}

// Round 2
// 736.728 us; speedup vs baseline: 7.9210x; 7.9210x over previous
//
#include <hip/hip_runtime.h>

#define NN 20000
#define NE 320000
#define FIN 64
#define HD 256
#define NC 10
#define NG 64

// ---------------- init: degi=0, pool=0, cnt=0 ----------------
__global__ void k_init(int* __restrict__ degi, float* __restrict__ pool, float* __restrict__ cnt) {
    int i = blockIdx.x * 256 + threadIdx.x;
    if (i < NN) degi[i] = 0;
    if (i < NG * HD) pool[i] = 0.0f;
    if (i < NG) cnt[i] = 0.0f;
}

// ---------------- degree count over edge targets (int) ----------------
__global__ void k_degcount(const int* __restrict__ col, int* __restrict__ degi) {
    int i = blockIdx.x * 256 + threadIdx.x;
    if (i < NE) atomicAdd(&degi[col[i]], 1);
}

// ---------------- single-block exclusive scan -> rowptr, cursor; dinv -----
__global__ __launch_bounds__(1024) void k_scan(const int* __restrict__ degi,
                                               int* __restrict__ rowptr,
                                               int* __restrict__ cursor,
                                               float* __restrict__ dinv) {
    __shared__ int wsum[16];
    __shared__ int carry;
    if (threadIdx.x == 0) carry = 0;
    __syncthreads();
    const int lane = threadIdx.x & 63;
    const int wid = threadIdx.x >> 6;
    for (int base = 0; base < NN; base += 1024) {
        int i = base + threadIdx.x;
        int v = (i < NN) ? degi[i] : 0;
        int x = v;
#pragma unroll
        for (int off = 1; off < 64; off <<= 1) {
            int y = __shfl_up(x, off);
            if (lane >= off) x += y;
        }
        if (lane == 63) wsum[wid] = x;
        __syncthreads();
        int woff = 0;
        for (int w = 0; w < wid; ++w) woff += wsum[w];
        int excl = carry + woff + x - v;
        if (i < NN) {
            rowptr[i] = excl;
            cursor[i] = excl;
            dinv[i] = rsqrtf((float)(1 + v));
        }
        __syncthreads();
        if (threadIdx.x == 0) {
            int tot = 0;
            for (int w = 0; w < 16; ++w) tot += wsum[w];
            carry += tot;
        }
        __syncthreads();
    }
    if (threadIdx.x == 0) rowptr[NN] = carry;
}

// ---------------- fill CSR buckets ----------------
__global__ void k_fill(const int* __restrict__ row, const int* __restrict__ col,
                       int* __restrict__ cursor, int* __restrict__ ebuf) {
    int e = blockIdx.x * 256 + threadIdx.x;
    if (e < NE) {
        int c = col[e];
        int pos = atomicAdd(&cursor[c], 1);
        ebuf[pos] = row[e];
    }
}

// ---------------- fp32 tiled matmul: Y = (A @ W) * dinv[row] ------
// A: [NN, K] row-major, W: [K, 256] row-major. Tile 64x64, BK=16.
__global__ __launch_bounds__(256) void k_matmul(const float* __restrict__ A,
                                                const float* __restrict__ W,
                                                const float* __restrict__ dinv,
                                                float* __restrict__ Y,
                                                int K) {
    __shared__ float As[16][64];
    __shared__ float Ws[16][64];
    const int m0 = blockIdx.x * 64;
    const int n0 = blockIdx.y * 64;
    const int t = threadIdx.x;
    const int tm = (t >> 4) << 2;
    const int tn = (t & 15) << 2;
    float acc[4][4] = {};

    const int la_m = t >> 2;
    const int la_k = (t & 3) << 2;
    const int lw_k = t >> 4;
    const int lw_n = (t & 15) << 2;

    for (int k0 = 0; k0 < K; k0 += 16) {
        float4 av;
        int gm = m0 + la_m;
        if (gm < NN) av = *(const float4*)&A[(size_t)gm * K + k0 + la_k];
        else av = make_float4(0.f, 0.f, 0.f, 0.f);
        As[la_k + 0][la_m] = av.x;
        As[la_k + 1][la_m] = av.y;
        As[la_k + 2][la_m] = av.z;
        As[la_k + 3][la_m] = av.w;
        *(float4*)&Ws[lw_k][lw_n] = *(const float4*)&W[(size_t)(k0 + lw_k) * HD + n0 + lw_n];
        __syncthreads();
#pragma unroll
        for (int k = 0; k < 16; ++k) {
            float4 a = *(const float4*)&As[k][tm];
            float4 w = *(const float4*)&Ws[k][tn];
            acc[0][0] = fmaf(a.x, w.x, acc[0][0]); acc[0][1] = fmaf(a.x, w.y, acc[0][1]);
            acc[0][2] = fmaf(a.x, w.z, acc[0][2]); acc[0][3] = fmaf(a.x, w.w, acc[0][3]);
            acc[1][0] = fmaf(a.y, w.x, acc[1][0]); acc[1][1] = fmaf(a.y, w.y, acc[1][1]);
            acc[1][2] = fmaf(a.y, w.z, acc[1][2]); acc[1][3] = fmaf(a.y, w.w, acc[1][3]);
            acc[2][0] = fmaf(a.z, w.x, acc[2][0]); acc[2][1] = fmaf(a.z, w.y, acc[2][1]);
            acc[2][2] = fmaf(a.z, w.z, acc[2][2]); acc[2][3] = fmaf(a.z, w.w, acc[2][3]);
            acc[3][0] = fmaf(a.w, w.x, acc[3][0]); acc[3][1] = fmaf(a.w, w.y, acc[3][1]);
            acc[3][2] = fmaf(a.w, w.z, acc[3][2]); acc[3][3] = fmaf(a.w, w.w, acc[3][3]);
        }
        __syncthreads();
    }
#pragma unroll
    for (int i = 0; i < 4; ++i) {
        int gm = m0 + tm + i;
        if (gm >= NN) break;
        float d = dinv[gm];
        float4 v = make_float4(acc[i][0] * d, acc[i][1] * d, acc[i][2] * d, acc[i][3] * d);
        *(float4*)&Y[(size_t)gm * HD + n0 + tn] = v;
    }
}

// ---------------- gather: h[n] = relu(dinv[n]*(Y[n] + sum_in Y[r]) + b) ----
__global__ __launch_bounds__(256) void k_gather(const float* __restrict__ Y,
                                                const int* __restrict__ rowptr,
                                                const int* __restrict__ ebuf,
                                                const float* __restrict__ dinv,
                                                const float* __restrict__ b,
                                                float* __restrict__ h) {
    int n = blockIdx.x * 4 + (threadIdx.x >> 6);
    int lane = threadIdx.x & 63;
    if (n >= NN) return;
    int s = rowptr[n], e = rowptr[n + 1];
    float4 acc = *(const float4*)&Y[(size_t)n * HD + lane * 4];  // self-loop
    for (int j = s; j < e; j += 64) {
        int myid = (j + lane < e) ? ebuf[j + lane] : 0;
        int cnt = min(64, e - j);
        for (int t = 0; t < cnt; ++t) {
            int r = __shfl(myid, t);
            const float4 v = *(const float4*)&Y[(size_t)r * HD + lane * 4];
            acc.x += v.x; acc.y += v.y; acc.z += v.z; acc.w += v.w;
        }
    }
    float d = dinv[n];
    float4 bb = *(const float4*)&b[lane * 4];
    float4 r;
    r.x = fmaxf(fmaf(acc.x, d, bb.x), 0.f);
    r.y = fmaxf(fmaf(acc.y, d, bb.y), 0.f);
    r.z = fmaxf(fmaf(acc.z, d, bb.z), 0.f);
    r.w = fmaxf(fmaf(acc.w, d, bb.w), 0.f);
    *(float4*)&h[(size_t)n * HD + lane * 4] = r;
}

// ---------------- pooling: pool[g] += h[n], cnt[g] += 1; one wave per node -
__global__ __launch_bounds__(256) void k_poolsum(const float* __restrict__ h,
                                                 const int* __restrict__ batch,
                                                 float* __restrict__ pool,
                                                 float* __restrict__ cnt) {
    int n = blockIdx.x * 4 + (threadIdx.x >> 6);
    int lane = threadIdx.x & 63;
    if (n >= NN) return;
    int g = batch[n];
    const float4 v = *(const float4*)&h[(size_t)n * HD + lane * 4];
    float* dst = &pool[(size_t)g * HD + lane * 4];
    atomicAdd(dst + 0, v.x);
    atomicAdd(dst + 1, v.y);
    atomicAdd(dst + 2, v.z);
    atomicAdd(dst + 3, v.w);
    if (lane == 0) atomicAdd(&cnt[g], 1.0f);
}

// ---------------- head ----------------
__global__ __launch_bounds__(64) void k_out(const float* __restrict__ pool,
                                            const float* __restrict__ cnt,
                                            const float* __restrict__ Wout,
                                            const float* __restrict__ bout,
                                            float* __restrict__ out) {
    int b = blockIdx.x;
    int g = b / NC;
    int c = b % NC;
    int lane = threadIdx.x;
    float s = 0.f;
#pragma unroll
    for (int j = 0; j < 4; ++j) {
        int f = lane * 4 + j;
        s = fmaf(pool[(size_t)g * HD + f], Wout[(size_t)f * NC + c], s);
    }
#pragma unroll
    for (int off = 32; off > 0; off >>= 1) s += __shfl_down(s, off);
    if (lane == 0) {
        float inv = 1.0f / fmaxf(cnt[g], 1.0f);
        out[(size_t)g * NC + c] = fmaf(s, inv, bout[c]);
    }
}

extern "C" void kernel_launch(void* const* d_in, const int* in_sizes, int n_in,
                              void* d_out, int out_size, void* d_ws, size_t ws_size,
                              hipStream_t stream) {
    const float* x     = (const float*)d_in[0];
    const int*   ei    = (const int*)d_in[1];
    const int*   batch = (const int*)d_in[2];
    const float* Wl[5] = {(const float*)d_in[3], (const float*)d_in[5], (const float*)d_in[7],
                          (const float*)d_in[9], (const float*)d_in[11]};
    const float* bl[5] = {(const float*)d_in[4], (const float*)d_in[6], (const float*)d_in[8],
                          (const float*)d_in[10], (const float*)d_in[12]};
    const float* Wout = (const float*)d_in[13];
    const float* bout = (const float*)d_in[14];
    float* out = (float*)d_out;

    const int* row = ei;
    const int* col = ei + NE;

    char* p = (char*)d_ws;
    auto take = [&](size_t bytes) { char* q = p; p += (bytes + 255) & ~(size_t)255; return q; };
    float* dinv   = (float*)take(NN * 4);
    int*   degi   = (int*)take(NN * 4);
    int*   rowptr = (int*)take((NN + 1) * 4);
    int*   cursor = (int*)take(NN * 4);
    int*   ebuf   = (int*)take(NE * 4);
    float* Y      = (float*)take((size_t)NN * HD * 4);
    float* h      = (float*)take((size_t)NN * HD * 4);
    float* pool   = (float*)take(NG * HD * 4);
    float* cnt    = (float*)take(NG * 4);

    // CSR build + degrees
    k_init<<<(NN + 255) / 256, 256, 0, stream>>>(degi, pool, cnt);
    k_degcount<<<(NE + 255) / 256, 256, 0, stream>>>(col, degi);
    k_scan<<<1, 1024, 0, stream>>>(degi, rowptr, cursor, dinv);
    k_fill<<<(NE + 255) / 256, 256, 0, stream>>>(row, col, cursor, ebuf);

    dim3 mmGrid((NN + 63) / 64, HD / 64);
    const float* Ain = x;
    int K = FIN;
    for (int l = 0; l < 5; ++l) {
        k_matmul<<<mmGrid, 256, 0, stream>>>(Ain, Wl[l], dinv, Y, K);
        k_gather<<<(NN + 3) / 4, 256, 0, stream>>>(Y, rowptr, ebuf, dinv, bl[l], h);
        Ain = h;
        K = HD;
    }

    k_poolsum<<<(NN + 3) / 4, 256, 0, stream>>>(h, batch, pool, cnt);
    k_out<<<NG * NC, 64, 0, stream>>>(pool, cnt, Wout, bout, out);
}

// Round 3
// 664.753 us; speedup vs baseline: 8.7787x; 1.1083x over previous
//
#include <hip/hip_runtime.h>

#define NN 20000
#define NE 320000
#define FIN 64
#define HD 256
#define NC 10
#define NG 64

// ---------------- init: degi=0, gstart=NN ----------------
__global__ void k_init(int* __restrict__ degi, int* __restrict__ gstart) {
    int i = blockIdx.x * 256 + threadIdx.x;
    if (i < NN) degi[i] = 0;
    if (i < NG) gstart[i] = NN;
}

// ---------------- degree count over edge targets (int) ----------------
__global__ void k_degcount(const int* __restrict__ col, int* __restrict__ degi) {
    int i = blockIdx.x * 256 + threadIdx.x;
    if (i < NE) atomicAdd(&degi[col[i]], 1);
}

// ---------------- graph start boundaries (batch is sorted) ----------------
__global__ void k_gbounds(const int* __restrict__ batch, int* __restrict__ gstart) {
    int n = blockIdx.x * 256 + threadIdx.x;
    if (n < NN) atomicMin(&gstart[batch[n]], n);
}

// ---------------- single-block exclusive scan -> rowptr, cursor; dinv -----
__global__ __launch_bounds__(1024) void k_scan(const int* __restrict__ degi,
                                               int* __restrict__ rowptr,
                                               int* __restrict__ cursor,
                                               float* __restrict__ dinv) {
    __shared__ int wsum[16];
    __shared__ int carry;
    if (threadIdx.x == 0) carry = 0;
    __syncthreads();
    const int lane = threadIdx.x & 63;
    const int wid = threadIdx.x >> 6;
    for (int base = 0; base < NN; base += 1024) {
        int i = base + threadIdx.x;
        int v = (i < NN) ? degi[i] : 0;
        int x = v;
#pragma unroll
        for (int off = 1; off < 64; off <<= 1) {
            int y = __shfl_up(x, off);
            if (lane >= off) x += y;
        }
        if (lane == 63) wsum[wid] = x;
        __syncthreads();
        int woff = 0;
        for (int w = 0; w < wid; ++w) woff += wsum[w];
        int excl = carry + woff + x - v;
        if (i < NN) {
            rowptr[i] = excl;
            cursor[i] = excl;
            dinv[i] = rsqrtf((float)(1 + v));
        }
        __syncthreads();
        if (threadIdx.x == 0) {
            int tot = 0;
            for (int w = 0; w < 16; ++w) tot += wsum[w];
            carry += tot;
        }
        __syncthreads();
    }
    if (threadIdx.x == 0) rowptr[NN] = carry;
}

// ---------------- fill CSR buckets ----------------
__global__ void k_fill(const int* __restrict__ row, const int* __restrict__ col,
                       int* __restrict__ cursor, int* __restrict__ ebuf) {
    int e = blockIdx.x * 256 + threadIdx.x;
    if (e < NE) {
        int c = col[e];
        int pos = atomicAdd(&cursor[c], 1);
        ebuf[pos] = row[e];
    }
}

// ---------------- fp32 tiled matmul: Y = (A @ W) * dinv[row] ------
__global__ __launch_bounds__(256) void k_matmul(const float* __restrict__ A,
                                                const float* __restrict__ W,
                                                const float* __restrict__ dinv,
                                                float* __restrict__ Y,
                                                int K) {
    __shared__ float As[16][64];
    __shared__ float Ws[16][64];
    const int m0 = blockIdx.x * 64;
    const int n0 = blockIdx.y * 64;
    const int t = threadIdx.x;
    const int tm = (t >> 4) << 2;
    const int tn = (t & 15) << 2;
    float acc[4][4] = {};

    const int la_m = t >> 2;
    const int la_k = (t & 3) << 2;
    const int lw_k = t >> 4;
    const int lw_n = (t & 15) << 2;

    for (int k0 = 0; k0 < K; k0 += 16) {
        float4 av;
        int gm = m0 + la_m;
        if (gm < NN) av = *(const float4*)&A[(size_t)gm * K + k0 + la_k];
        else av = make_float4(0.f, 0.f, 0.f, 0.f);
        As[la_k + 0][la_m] = av.x;
        As[la_k + 1][la_m] = av.y;
        As[la_k + 2][la_m] = av.z;
        As[la_k + 3][la_m] = av.w;
        *(float4*)&Ws[lw_k][lw_n] = *(const float4*)&W[(size_t)(k0 + lw_k) * HD + n0 + lw_n];
        __syncthreads();
#pragma unroll
        for (int k = 0; k < 16; ++k) {
            float4 a = *(const float4*)&As[k][tm];
            float4 w = *(const float4*)&Ws[k][tn];
            acc[0][0] = fmaf(a.x, w.x, acc[0][0]); acc[0][1] = fmaf(a.x, w.y, acc[0][1]);
            acc[0][2] = fmaf(a.x, w.z, acc[0][2]); acc[0][3] = fmaf(a.x, w.w, acc[0][3]);
            acc[1][0] = fmaf(a.y, w.x, acc[1][0]); acc[1][1] = fmaf(a.y, w.y, acc[1][1]);
            acc[1][2] = fmaf(a.y, w.z, acc[1][2]); acc[1][3] = fmaf(a.y, w.w, acc[1][3]);
            acc[2][0] = fmaf(a.z, w.x, acc[2][0]); acc[2][1] = fmaf(a.z, w.y, acc[2][1]);
            acc[2][2] = fmaf(a.z, w.z, acc[2][2]); acc[2][3] = fmaf(a.z, w.w, acc[2][3]);
            acc[3][0] = fmaf(a.w, w.x, acc[3][0]); acc[3][1] = fmaf(a.w, w.y, acc[3][1]);
            acc[3][2] = fmaf(a.w, w.z, acc[3][2]); acc[3][3] = fmaf(a.w, w.w, acc[3][3]);
        }
        __syncthreads();
    }
#pragma unroll
    for (int i = 0; i < 4; ++i) {
        int gm = m0 + tm + i;
        if (gm >= NN) break;
        float d = dinv[gm];
        float4 v = make_float4(acc[i][0] * d, acc[i][1] * d, acc[i][2] * d, acc[i][3] * d);
        *(float4*)&Y[(size_t)gm * HD + n0 + tn] = v;
    }
}

// ---------------- gather: h[n] = relu(dinv[n]*(Y[n] + sum_in Y[r]) + b) ----
__global__ __launch_bounds__(256) void k_gather(const float* __restrict__ Y,
                                                const int* __restrict__ rowptr,
                                                const int* __restrict__ ebuf,
                                                const float* __restrict__ dinv,
                                                const float* __restrict__ b,
                                                float* __restrict__ h) {
    int n = blockIdx.x * 4 + (threadIdx.x >> 6);
    int lane = threadIdx.x & 63;
    if (n >= NN) return;
    int s = rowptr[n], e = rowptr[n + 1];
    float4 acc = *(const float4*)&Y[(size_t)n * HD + lane * 4];  // self-loop
    for (int j = s; j < e; j += 64) {
        int myid = (j + lane < e) ? ebuf[j + lane] : 0;
        int cnt = min(64, e - j);
        for (int t = 0; t < cnt; ++t) {
            int r = __shfl(myid, t);
            const float4 v = *(const float4*)&Y[(size_t)r * HD + lane * 4];
            acc.x += v.x; acc.y += v.y; acc.z += v.z; acc.w += v.w;
        }
    }
    float d = dinv[n];
    float4 bb = *(const float4*)&b[lane * 4];
    float4 r;
    r.x = fmaxf(fmaf(acc.x, d, bb.x), 0.f);
    r.y = fmaxf(fmaf(acc.y, d, bb.y), 0.f);
    r.z = fmaxf(fmaf(acc.z, d, bb.z), 0.f);
    r.w = fmaxf(fmaf(acc.w, d, bb.w), 0.f);
    *(float4*)&h[(size_t)n * HD + lane * 4] = r;
}

// ---------------- pooling: one block per (graph, 64-feat chunk), no atomics
__global__ __launch_bounds__(256) void k_pool(const float* __restrict__ h,
                                              const int* __restrict__ gstart,
                                              float* __restrict__ pool) {
    int g = blockIdx.x;
    int f0 = blockIdx.y * 64;
    int tx = threadIdx.x & 63;
    int ty = threadIdx.x >> 6;
    __shared__ int s_start, s_end;
    __shared__ float red[4][64];
    if (threadIdx.x == 0) {
        int st = gstart[g];
        int en = NN;
        for (int gg = g + 1; gg < NG; ++gg) en = min(en, gstart[gg]);
        s_start = st;
        s_end = en;
    }
    __syncthreads();
    int st = s_start, en = s_end;
    float acc = 0.f;
    for (int n = st + ty; n < en; n += 4)
        acc += h[(size_t)n * HD + f0 + tx];
    red[ty][tx] = acc;
    __syncthreads();
    if (ty == 0) {
        float s = red[0][tx] + red[1][tx] + red[2][tx] + red[3][tx];
        int cnt = en - st;
        float inv = 1.0f / (float)max(cnt, 1);
        pool[(size_t)g * HD + f0 + tx] = s * inv;
    }
}

// ---------------- head: out[g][c] = pool[g] . Wout[:,c] + bout[c] ----------
__global__ __launch_bounds__(64) void k_out(const float* __restrict__ pool,
                                            const float* __restrict__ Wout,
                                            const float* __restrict__ bout,
                                            float* __restrict__ out) {
    int b = blockIdx.x;
    int g = b / NC;
    int c = b % NC;
    int lane = threadIdx.x;
    float s = 0.f;
#pragma unroll
    for (int j = 0; j < 4; ++j) {
        int f = lane * 4 + j;
        s = fmaf(pool[(size_t)g * HD + f], Wout[(size_t)f * NC + c], s);
    }
#pragma unroll
    for (int off = 32; off > 0; off >>= 1) s += __shfl_down(s, off);
    if (lane == 0) out[(size_t)g * NC + c] = s + bout[c];
}

extern "C" void kernel_launch(void* const* d_in, const int* in_sizes, int n_in,
                              void* d_out, int out_size, void* d_ws, size_t ws_size,
                              hipStream_t stream) {
    const float* x     = (const float*)d_in[0];
    const int*   ei    = (const int*)d_in[1];
    const int*   batch = (const int*)d_in[2];
    const float* Wl[5] = {(const float*)d_in[3], (const float*)d_in[5], (const float*)d_in[7],
                          (const float*)d_in[9], (const float*)d_in[11]};
    const float* bl[5] = {(const float*)d_in[4], (const float*)d_in[6], (const float*)d_in[8],
                          (const float*)d_in[10], (const float*)d_in[12]};
    const float* Wout = (const float*)d_in[13];
    const float* bout = (const float*)d_in[14];
    float* out = (float*)d_out;

    const int* row = ei;
    const int* col = ei + NE;

    char* p = (char*)d_ws;
    auto take = [&](size_t bytes) { char* q = p; p += (bytes + 255) & ~(size_t)255; return q; };
    float* dinv   = (float*)take(NN * 4);
    int*   degi   = (int*)take(NN * 4);
    int*   rowptr = (int*)take((NN + 1) * 4);
    int*   cursor = (int*)take(NN * 4);
    int*   ebuf   = (int*)take(NE * 4);
    int*   gstart = (int*)take(NG * 4);
    float* Y      = (float*)take((size_t)NN * HD * 4);
    float* h      = (float*)take((size_t)NN * HD * 4);
    float* pool   = (float*)take(NG * HD * 4);

    // CSR build + degrees + graph bounds
    k_init<<<(NN + 255) / 256, 256, 0, stream>>>(degi, gstart);
    k_degcount<<<(NE + 255) / 256, 256, 0, stream>>>(col, degi);
    k_gbounds<<<(NN + 255) / 256, 256, 0, stream>>>(batch, gstart);
    k_scan<<<1, 1024, 0, stream>>>(degi, rowptr, cursor, dinv);
    k_fill<<<(NE + 255) / 256, 256, 0, stream>>>(row, col, cursor, ebuf);

    dim3 mmGrid((NN + 63) / 64, HD / 64);
    const float* Ain = x;
    int K = FIN;
    for (int l = 0; l < 5; ++l) {
        k_matmul<<<mmGrid, 256, 0, stream>>>(Ain, Wl[l], dinv, Y, K);
        k_gather<<<(NN + 3) / 4, 256, 0, stream>>>(Y, rowptr, ebuf, dinv, bl[l], h);
        Ain = h;
        K = HD;
    }

    dim3 poolGrid(NG, HD / 64);
    k_pool<<<poolGrid, 256, 0, stream>>>(h, gstart, pool);
    k_out<<<NG * NC, 64, 0, stream>>>(pool, Wout, bout, out);
}

// Round 4
// 569.507 us; speedup vs baseline: 10.2469x; 1.1672x over previous
//
#include <hip/hip_runtime.h>

#define NN 20000
#define NE 320000
#define FIN 64
#define HD 256
#define NC 10
#define NG 64

// ---------------- init: degi=0, gstart=NN ----------------
__global__ void k_init(int* __restrict__ degi, int* __restrict__ gstart) {
    int i = blockIdx.x * 256 + threadIdx.x;
    if (i < NN) degi[i] = 0;
    if (i < NG) gstart[i] = NN;
}

// ---------------- degree count over edge targets (int) ----------------
__global__ void k_degcount(const int* __restrict__ col, int* __restrict__ degi) {
    int i = blockIdx.x * 256 + threadIdx.x;
    if (i < NE) atomicAdd(&degi[col[i]], 1);
}

// ---------------- graph start boundaries (batch sorted, no atomics) -------
__global__ void k_gbounds(const int* __restrict__ batch, int* __restrict__ gstart) {
    int n = blockIdx.x * 256 + threadIdx.x;
    if (n >= NN) return;
    int b = batch[n];
    int prev = (n == 0) ? -1 : batch[n - 1];
    if (b != prev) gstart[b] = n;   // exactly one writer per graph
}

// ---------------- single-block exclusive scan -> rowptr, cursor; dinv -----
__global__ __launch_bounds__(1024) void k_scan(const int* __restrict__ degi,
                                               int* __restrict__ rowptr,
                                               int* __restrict__ cursor,
                                               float* __restrict__ dinv) {
    __shared__ int wsum[16];
    __shared__ int carry;
    if (threadIdx.x == 0) carry = 0;
    __syncthreads();
    const int lane = threadIdx.x & 63;
    const int wid = threadIdx.x >> 6;
    for (int base = 0; base < NN; base += 1024) {
        int i = base + threadIdx.x;
        int v = (i < NN) ? degi[i] : 0;
        int x = v;
#pragma unroll
        for (int off = 1; off < 64; off <<= 1) {
            int y = __shfl_up(x, off);
            if (lane >= off) x += y;
        }
        if (lane == 63) wsum[wid] = x;
        __syncthreads();
        int woff = 0;
        for (int w = 0; w < wid; ++w) woff += wsum[w];
        int excl = carry + woff + x - v;
        if (i < NN) {
            rowptr[i] = excl;
            cursor[i] = excl;
            dinv[i] = rsqrtf((float)(1 + v));
        }
        __syncthreads();
        if (threadIdx.x == 0) {
            int tot = 0;
            for (int w = 0; w < 16; ++w) tot += wsum[w];
            carry += tot;
        }
        __syncthreads();
    }
    if (threadIdx.x == 0) rowptr[NN] = carry;
}

// ---------------- fill CSR buckets ----------------
__global__ void k_fill(const int* __restrict__ row, const int* __restrict__ col,
                       int* __restrict__ cursor, int* __restrict__ ebuf) {
    int e = blockIdx.x * 256 + threadIdx.x;
    if (e < NE) {
        int c = col[e];
        int pos = atomicAdd(&cursor[c], 1);
        ebuf[pos] = row[e];
    }
}

// ---------------- fp32 tiled matmul: Y = (A @ W) * dinv[row] ------
__global__ __launch_bounds__(256) void k_matmul(const float* __restrict__ A,
                                                const float* __restrict__ W,
                                                const float* __restrict__ dinv,
                                                float* __restrict__ Y,
                                                int K) {
    __shared__ float As[16][64];
    __shared__ float Ws[16][64];
    const int m0 = blockIdx.x * 64;
    const int n0 = blockIdx.y * 64;
    const int t = threadIdx.x;
    const int tm = (t >> 4) << 2;
    const int tn = (t & 15) << 2;
    float acc[4][4] = {};

    const int la_m = t >> 2;
    const int la_k = (t & 3) << 2;
    const int lw_k = t >> 4;
    const int lw_n = (t & 15) << 2;

    for (int k0 = 0; k0 < K; k0 += 16) {
        float4 av;
        int gm = m0 + la_m;
        if (gm < NN) av = *(const float4*)&A[(size_t)gm * K + k0 + la_k];
        else av = make_float4(0.f, 0.f, 0.f, 0.f);
        As[la_k + 0][la_m] = av.x;
        As[la_k + 1][la_m] = av.y;
        As[la_k + 2][la_m] = av.z;
        As[la_k + 3][la_m] = av.w;
        *(float4*)&Ws[lw_k][lw_n] = *(const float4*)&W[(size_t)(k0 + lw_k) * HD + n0 + lw_n];
        __syncthreads();
#pragma unroll
        for (int k = 0; k < 16; ++k) {
            float4 a = *(const float4*)&As[k][tm];
            float4 w = *(const float4*)&Ws[k][tn];
            acc[0][0] = fmaf(a.x, w.x, acc[0][0]); acc[0][1] = fmaf(a.x, w.y, acc[0][1]);
            acc[0][2] = fmaf(a.x, w.z, acc[0][2]); acc[0][3] = fmaf(a.x, w.w, acc[0][3]);
            acc[1][0] = fmaf(a.y, w.x, acc[1][0]); acc[1][1] = fmaf(a.y, w.y, acc[1][1]);
            acc[1][2] = fmaf(a.y, w.z, acc[1][2]); acc[1][3] = fmaf(a.y, w.w, acc[1][3]);
            acc[2][0] = fmaf(a.z, w.x, acc[2][0]); acc[2][1] = fmaf(a.z, w.y, acc[2][1]);
            acc[2][2] = fmaf(a.z, w.z, acc[2][2]); acc[2][3] = fmaf(a.z, w.w, acc[2][3]);
            acc[3][0] = fmaf(a.w, w.x, acc[3][0]); acc[3][1] = fmaf(a.w, w.y, acc[3][1]);
            acc[3][2] = fmaf(a.w, w.z, acc[3][2]); acc[3][3] = fmaf(a.w, w.w, acc[3][3]);
        }
        __syncthreads();
    }
#pragma unroll
    for (int i = 0; i < 4; ++i) {
        int gm = m0 + tm + i;
        if (gm >= NN) break;
        float d = dinv[gm];
        float4 v = make_float4(acc[i][0] * d, acc[i][1] * d, acc[i][2] * d, acc[i][3] * d);
        *(float4*)&Y[(size_t)gm * HD + n0 + tn] = v;
    }
}

// ---------------- gather: h[n] = relu(dinv[n]*(Y[n] + sum_in Y[r]) + b) ----
__global__ __launch_bounds__(256) void k_gather(const float* __restrict__ Y,
                                                const int* __restrict__ rowptr,
                                                const int* __restrict__ ebuf,
                                                const float* __restrict__ dinv,
                                                const float* __restrict__ b,
                                                float* __restrict__ h) {
    int n = blockIdx.x * 4 + (threadIdx.x >> 6);
    int lane = threadIdx.x & 63;
    if (n >= NN) return;
    int s = rowptr[n], e = rowptr[n + 1];
    float4 acc = *(const float4*)&Y[(size_t)n * HD + lane * 4];  // self-loop
    for (int j = s; j < e; j += 64) {
        int myid = (j + lane < e) ? ebuf[j + lane] : 0;
        int cnt = min(64, e - j);
        for (int t = 0; t < cnt; ++t) {
            int r = __shfl(myid, t);
            const float4 v = *(const float4*)&Y[(size_t)r * HD + lane * 4];
            acc.x += v.x; acc.y += v.y; acc.z += v.z; acc.w += v.w;
        }
    }
    float d = dinv[n];
    float4 bb = *(const float4*)&b[lane * 4];
    float4 r;
    r.x = fmaxf(fmaf(acc.x, d, bb.x), 0.f);
    r.y = fmaxf(fmaf(acc.y, d, bb.y), 0.f);
    r.z = fmaxf(fmaf(acc.z, d, bb.z), 0.f);
    r.w = fmaxf(fmaf(acc.w, d, bb.w), 0.f);
    *(float4*)&h[(size_t)n * HD + lane * 4] = r;
}

// ---------------- pooling: one block per (graph, 64-feat chunk), no atomics
__global__ __launch_bounds__(256) void k_pool(const float* __restrict__ h,
                                              const int* __restrict__ gstart,
                                              float* __restrict__ pool) {
    int g = blockIdx.x;
    int f0 = blockIdx.y * 64;
    int tx = threadIdx.x & 63;
    int ty = threadIdx.x >> 6;
    __shared__ int s_start, s_end;
    __shared__ float red[4][64];
    if (threadIdx.x == 0) {
        int st = gstart[g];
        int en = NN;
        for (int gg = g + 1; gg < NG; ++gg) en = min(en, gstart[gg]);
        s_start = st;
        s_end = en;
    }
    __syncthreads();
    int st = s_start, en = s_end;
    float acc = 0.f;
    for (int n = st + ty; n < en; n += 4)
        acc += h[(size_t)n * HD + f0 + tx];
    red[ty][tx] = acc;
    __syncthreads();
    if (ty == 0) {
        float s = red[0][tx] + red[1][tx] + red[2][tx] + red[3][tx];
        int cnt = en - st;
        float inv = 1.0f / (float)max(cnt, 1);
        pool[(size_t)g * HD + f0 + tx] = s * inv;
    }
}

// ---------------- head: out[g][c] = pool[g] . Wout[:,c] + bout[c] ----------
__global__ __launch_bounds__(64) void k_out(const float* __restrict__ pool,
                                            const float* __restrict__ Wout,
                                            const float* __restrict__ bout,
                                            float* __restrict__ out) {
    int b = blockIdx.x;
    int g = b / NC;
    int c = b % NC;
    int lane = threadIdx.x;
    float s = 0.f;
#pragma unroll
    for (int j = 0; j < 4; ++j) {
        int f = lane * 4 + j;
        s = fmaf(pool[(size_t)g * HD + f], Wout[(size_t)f * NC + c], s);
    }
#pragma unroll
    for (int off = 32; off > 0; off >>= 1) s += __shfl_down(s, off);
    if (lane == 0) out[(size_t)g * NC + c] = s + bout[c];
}

extern "C" void kernel_launch(void* const* d_in, const int* in_sizes, int n_in,
                              void* d_out, int out_size, void* d_ws, size_t ws_size,
                              hipStream_t stream) {
    const float* x     = (const float*)d_in[0];
    const int*   ei    = (const int*)d_in[1];
    const int*   batch = (const int*)d_in[2];
    const float* Wl[5] = {(const float*)d_in[3], (const float*)d_in[5], (const float*)d_in[7],
                          (const float*)d_in[9], (const float*)d_in[11]};
    const float* bl[5] = {(const float*)d_in[4], (const float*)d_in[6], (const float*)d_in[8],
                          (const float*)d_in[10], (const float*)d_in[12]};
    const float* Wout = (const float*)d_in[13];
    const float* bout = (const float*)d_in[14];
    float* out = (float*)d_out;

    const int* row = ei;
    const int* col = ei + NE;

    char* p = (char*)d_ws;
    auto take = [&](size_t bytes) { char* q = p; p += (bytes + 255) & ~(size_t)255; return q; };
    float* dinv   = (float*)take(NN * 4);
    int*   degi   = (int*)take(NN * 4);
    int*   rowptr = (int*)take((NN + 1) * 4);
    int*   cursor = (int*)take(NN * 4);
    int*   ebuf   = (int*)take(NE * 4);
    int*   gstart = (int*)take(NG * 4);
    float* Y      = (float*)take((size_t)NN * HD * 4);
    float* h      = (float*)take((size_t)NN * HD * 4);
    float* pool   = (float*)take(NG * HD * 4);

    // CSR build + degrees + graph bounds
    k_init<<<(NN + 255) / 256, 256, 0, stream>>>(degi, gstart);
    k_degcount<<<(NE + 255) / 256, 256, 0, stream>>>(col, degi);
    k_gbounds<<<(NN + 255) / 256, 256, 0, stream>>>(batch, gstart);
    k_scan<<<1, 1024, 0, stream>>>(degi, rowptr, cursor, dinv);
    k_fill<<<(NE + 255) / 256, 256, 0, stream>>>(row, col, cursor, ebuf);

    dim3 mmGrid((NN + 63) / 64, HD / 64);
    const float* Ain = x;
    int K = FIN;
    for (int l = 0; l < 5; ++l) {
        k_matmul<<<mmGrid, 256, 0, stream>>>(Ain, Wl[l], dinv, Y, K);
        k_gather<<<(NN + 3) / 4, 256, 0, stream>>>(Y, rowptr, ebuf, dinv, bl[l], h);
        Ain = h;
        K = HD;
    }

    dim3 poolGrid(NG, HD / 64);
    k_pool<<<poolGrid, 256, 0, stream>>>(h, gstart, pool);
    k_out<<<NG * NC, 64, 0, stream>>>(pool, Wout, bout, out);
}

// Round 5
// 424.245 us; speedup vs baseline: 13.7554x; 1.3424x over previous
//
#include <hip/hip_runtime.h>

#define NN 20000
#define NE 320000
#define FIN 64
#define HD 256
#define NC 10
#define NG 64

typedef unsigned short u16;
typedef unsigned int u32;
typedef __attribute__((ext_vector_type(8))) short short8;   // 8 bf16 (4 VGPRs)
typedef __attribute__((ext_vector_type(4))) float f32x4;    // 4 fp32 acc

__device__ __forceinline__ float bf2f(u16 u) {
    union { u32 i; float f; } v; v.i = ((u32)u) << 16; return v.f;
}
__device__ __forceinline__ u16 f2bf(float f) {
    union { float f; u32 i; } v; v.f = f;
    u32 r = v.i + 0x7fffu + ((v.i >> 16) & 1u);   // RNE
    return (u16)(r >> 16);
}

// ---------------- init: degi=0, gstart=NN ----------------
__global__ void k_init(int* __restrict__ degi, int* __restrict__ gstart) {
    int i = blockIdx.x * 256 + threadIdx.x;
    if (i < NN) degi[i] = 0;
    if (i < NG) gstart[i] = NN;
}

// ---------------- degree count over edge targets ----------------
__global__ void k_degcount(const int* __restrict__ col, int* __restrict__ degi) {
    int i = blockIdx.x * 256 + threadIdx.x;
    if (i < NE) atomicAdd(&degi[col[i]], 1);
}

// ---------------- graph start boundaries (batch sorted, no atomics) -------
__global__ void k_gbounds(const int* __restrict__ batch, int* __restrict__ gstart) {
    int n = blockIdx.x * 256 + threadIdx.x;
    if (n >= NN) return;
    int b = batch[n];
    int prev = (n == 0) ? -1 : batch[n - 1];
    if (b != prev) gstart[b] = n;
}

// ---------------- single-block exclusive scan -> rowptr, cursor; dinv -----
__global__ __launch_bounds__(1024) void k_scan(const int* __restrict__ degi,
                                               int* __restrict__ rowptr,
                                               int* __restrict__ cursor,
                                               float* __restrict__ dinv) {
    __shared__ int wsum[16];
    __shared__ int carry;
    if (threadIdx.x == 0) carry = 0;
    __syncthreads();
    const int lane = threadIdx.x & 63;
    const int wid = threadIdx.x >> 6;
    for (int base = 0; base < NN; base += 1024) {
        int i = base + threadIdx.x;
        int v = (i < NN) ? degi[i] : 0;
        int x = v;
#pragma unroll
        for (int off = 1; off < 64; off <<= 1) {
            int y = __shfl_up(x, off);
            if (lane >= off) x += y;
        }
        if (lane == 63) wsum[wid] = x;
        __syncthreads();
        int woff = 0;
        for (int w = 0; w < wid; ++w) woff += wsum[w];
        int excl = carry + woff + x - v;
        if (i < NN) {
            rowptr[i] = excl;
            cursor[i] = excl;
            dinv[i] = rsqrtf((float)(1 + v));
        }
        __syncthreads();
        if (threadIdx.x == 0) {
            int tot = 0;
            for (int w = 0; w < 16; ++w) tot += wsum[w];
            carry += tot;
        }
        __syncthreads();
    }
    if (threadIdx.x == 0) rowptr[NN] = carry;
}

// ---------------- fill CSR buckets ----------------
__global__ void k_fill(const int* __restrict__ row, const int* __restrict__ col,
                       int* __restrict__ cursor, int* __restrict__ ebuf) {
    int e = blockIdx.x * 256 + threadIdx.x;
    if (e < NE) {
        int c = col[e];
        int pos = atomicAdd(&cursor[c], 1);
        ebuf[pos] = row[e];
    }
}

// ---------------- cast x fp32 -> bf16 ----------------
__global__ void k_xcast(const float* __restrict__ x, u16* __restrict__ h) {
    int i = blockIdx.x * 256 + threadIdx.x;   // one float4 -> 4 bf16 per thread
    if (i >= NN * FIN / 4) return;
    float4 v = *(const float4*)&x[(size_t)i * 4];
    u32 lo = (u32)f2bf(v.x) | ((u32)f2bf(v.y) << 16);
    u32 hi = (u32)f2bf(v.z) | ((u32)f2bf(v.w) << 16);
    *(uint2*)&h[(size_t)i * 4] = make_uint2(lo, hi);
}

// ---------------- cast + transpose W[k][256] -> Wt[n][K] bf16 ----------------
__global__ void k_wt(const float* __restrict__ W, u16* __restrict__ Wt, int K) {
    int idx = blockIdx.x * 256 + threadIdx.x;
    if (idx >= 256 * K) return;
    int n = idx / K;
    int k = idx - n * K;
    Wt[idx] = f2bf(W[(size_t)k * HD + n]);
}

// ---------------- MFMA matmul: Y[m][n] = bf16(dinv[m] * (A @ Wt^T)[m][n]) --
// A: [NN][K] bf16 row-major. Wt: [256][K] bf16 (i.e. B transposed, k contiguous).
// Block: 256 thr = 4 waves; tile M=64, N=256 (wave w covers n0=64w).
__global__ __launch_bounds__(256) void k_mm(const u16* __restrict__ A,
                                            const u16* __restrict__ Wt,
                                            const float* __restrict__ dinv,
                                            u16* __restrict__ Y,
                                            int K) {
    __shared__ u16 Asm[64][40];    // rows padded to 80 B: 16-B aligned, 2-way-bank max (free)
    __shared__ u16 Bsm[256][40];
    const int m0 = blockIdx.x * 64;
    const int t = threadIdx.x;
    const int wave = t >> 6;
    const int lane = t & 63;
    const int quad = lane >> 4;
    const int l16 = lane & 15;
    const int n0 = wave * 64;

    f32x4 acc[4][4];
#pragma unroll
    for (int i = 0; i < 4; ++i)
#pragma unroll
        for (int j = 0; j < 4; ++j) acc[i][j] = (f32x4){0.f, 0.f, 0.f, 0.f};

    for (int k0 = 0; k0 < K; k0 += 32) {
        // stage A tile [64][32]: thread -> row t>>2, 16-B segment t&3
        {
            int row = t >> 2, seg = t & 3;
            int gm = m0 + row;
            float4 v = make_float4(0.f, 0.f, 0.f, 0.f);
            if (gm < NN) v = *(const float4*)&A[(size_t)gm * K + k0 + seg * 8];
            *(float4*)&Asm[row][seg * 8] = v;
        }
        // stage B tile [256][32]: thread t loads 64 B of Wt row t
        {
#pragma unroll
            for (int j = 0; j < 4; ++j) {
                float4 v = *(const float4*)&Wt[(size_t)t * K + k0 + j * 8];
                *(float4*)&Bsm[t][j * 8] = v;
            }
        }
        __syncthreads();
        short8 a[4], b[4];
#pragma unroll
        for (int i = 0; i < 4; ++i) a[i] = *(const short8*)&Asm[i * 16 + l16][quad * 8];
#pragma unroll
        for (int j = 0; j < 4; ++j) b[j] = *(const short8*)&Bsm[n0 + j * 16 + l16][quad * 8];
#pragma unroll
        for (int i = 0; i < 4; ++i)
#pragma unroll
            for (int j = 0; j < 4; ++j)
                acc[i][j] = __builtin_amdgcn_mfma_f32_16x16x32_bf16(a[i], b[j], acc[i][j], 0, 0, 0);
        __syncthreads();
    }
    // epilogue: C/D layout col=lane&15, row=quad*4+reg
#pragma unroll
    for (int i = 0; i < 4; ++i) {
#pragma unroll
        for (int r = 0; r < 4; ++r) {
            int m = m0 + i * 16 + quad * 4 + r;
            if (m >= NN) continue;
            float d = dinv[m];
#pragma unroll
            for (int j = 0; j < 4; ++j) {
                int n = n0 + j * 16 + l16;
                Y[(size_t)m * HD + n] = f2bf(acc[i][j][r] * d);
            }
        }
    }
}

// ---------------- gather: h[n] = bf16(relu(dinv[n]*(Y[n]+sum Y[r]) + b)) ---
__global__ __launch_bounds__(256) void k_gather(const u16* __restrict__ Y,
                                                const int* __restrict__ rowptr,
                                                const int* __restrict__ ebuf,
                                                const float* __restrict__ dinv,
                                                const float* __restrict__ b,
                                                u16* __restrict__ h) {
    int n = blockIdx.x * 4 + (threadIdx.x >> 6);
    int lane = threadIdx.x & 63;
    if (n >= NN) return;
    int s = rowptr[n], e = rowptr[n + 1];
    uint2 raw = *(const uint2*)&Y[(size_t)n * HD + lane * 4];  // self-loop
    float4 acc;
    acc.x = bf2f((u16)(raw.x & 0xffff)); acc.y = bf2f((u16)(raw.x >> 16));
    acc.z = bf2f((u16)(raw.y & 0xffff)); acc.w = bf2f((u16)(raw.y >> 16));
    for (int j = s; j < e; j += 64) {
        int myid = (j + lane < e) ? ebuf[j + lane] : 0;
        int cnt = min(64, e - j);
        for (int t = 0; t < cnt; ++t) {
            int r = __shfl(myid, t);
            uint2 v = *(const uint2*)&Y[(size_t)r * HD + lane * 4];
            acc.x += bf2f((u16)(v.x & 0xffff)); acc.y += bf2f((u16)(v.x >> 16));
            acc.z += bf2f((u16)(v.y & 0xffff)); acc.w += bf2f((u16)(v.y >> 16));
        }
    }
    float d = dinv[n];
    float4 bb = *(const float4*)&b[lane * 4];
    float rx = fmaxf(fmaf(acc.x, d, bb.x), 0.f);
    float ry = fmaxf(fmaf(acc.y, d, bb.y), 0.f);
    float rz = fmaxf(fmaf(acc.z, d, bb.z), 0.f);
    float rw = fmaxf(fmaf(acc.w, d, bb.w), 0.f);
    u32 lo = (u32)f2bf(rx) | ((u32)f2bf(ry) << 16);
    u32 hi = (u32)f2bf(rz) | ((u32)f2bf(rw) << 16);
    *(uint2*)&h[(size_t)n * HD + lane * 4] = make_uint2(lo, hi);
}

// ---------------- pooling: one block per (graph, 64-feat chunk) ------------
__global__ __launch_bounds__(256) void k_pool(const u16* __restrict__ h,
                                              const int* __restrict__ gstart,
                                              float* __restrict__ pool) {
    int g = blockIdx.x;
    int f0 = blockIdx.y * 64;
    int tx = threadIdx.x & 63;
    int ty = threadIdx.x >> 6;
    __shared__ int s_start, s_end;
    __shared__ float red[4][64];
    if (threadIdx.x == 0) {
        int st = gstart[g];
        int en = NN;
        for (int gg = g + 1; gg < NG; ++gg) en = min(en, gstart[gg]);
        s_start = st;
        s_end = en;
    }
    __syncthreads();
    int st = s_start, en = s_end;
    float acc = 0.f;
    for (int n = st + ty; n < en; n += 4)
        acc += bf2f(h[(size_t)n * HD + f0 + tx]);
    red[ty][tx] = acc;
    __syncthreads();
    if (ty == 0) {
        float s = red[0][tx] + red[1][tx] + red[2][tx] + red[3][tx];
        int cnt = en - st;
        float inv = 1.0f / (float)max(cnt, 1);
        pool[(size_t)g * HD + f0 + tx] = s * inv;
    }
}

// ---------------- head ----------------
__global__ __launch_bounds__(64) void k_out(const float* __restrict__ pool,
                                            const float* __restrict__ Wout,
                                            const float* __restrict__ bout,
                                            float* __restrict__ out) {
    int bk = blockIdx.x;
    int g = bk / NC;
    int c = bk % NC;
    int lane = threadIdx.x;
    float s = 0.f;
#pragma unroll
    for (int j = 0; j < 4; ++j) {
        int f = lane * 4 + j;
        s = fmaf(pool[(size_t)g * HD + f], Wout[(size_t)f * NC + c], s);
    }
#pragma unroll
    for (int off = 32; off > 0; off >>= 1) s += __shfl_down(s, off);
    if (lane == 0) out[(size_t)g * NC + c] = s + bout[c];
}

extern "C" void kernel_launch(void* const* d_in, const int* in_sizes, int n_in,
                              void* d_out, int out_size, void* d_ws, size_t ws_size,
                              hipStream_t stream) {
    const float* x     = (const float*)d_in[0];
    const int*   ei    = (const int*)d_in[1];
    const int*   batch = (const int*)d_in[2];
    const float* Wl[5] = {(const float*)d_in[3], (const float*)d_in[5], (const float*)d_in[7],
                          (const float*)d_in[9], (const float*)d_in[11]};
    const float* bl[5] = {(const float*)d_in[4], (const float*)d_in[6], (const float*)d_in[8],
                          (const float*)d_in[10], (const float*)d_in[12]};
    const float* Wout = (const float*)d_in[13];
    const float* bout = (const float*)d_in[14];
    float* out = (float*)d_out;

    const int* row = ei;
    const int* col = ei + NE;

    char* p = (char*)d_ws;
    auto take = [&](size_t bytes) { char* q = p; p += (bytes + 255) & ~(size_t)255; return q; };
    float* dinv   = (float*)take(NN * 4);
    int*   degi   = (int*)take(NN * 4);
    int*   rowptr = (int*)take((NN + 1) * 4);
    int*   cursor = (int*)take(NN * 4);
    int*   ebuf   = (int*)take(NE * 4);
    int*   gstart = (int*)take(NG * 4);
    u16*   Wt[5];
    for (int l = 0; l < 5; ++l) Wt[l] = (u16*)take((size_t)HD * HD * 2);
    u16*   hA     = (u16*)take((size_t)NN * HD * 2);
    u16*   Y      = (u16*)take((size_t)NN * HD * 2);
    float* pool   = (float*)take(NG * HD * 4);

    // CSR build + degrees + graph bounds
    k_init<<<(NN + 255) / 256, 256, 0, stream>>>(degi, gstart);
    k_degcount<<<(NE + 255) / 256, 256, 0, stream>>>(col, degi);
    k_gbounds<<<(NN + 255) / 256, 256, 0, stream>>>(batch, gstart);
    k_scan<<<1, 1024, 0, stream>>>(degi, rowptr, cursor, dinv);
    k_fill<<<(NE + 255) / 256, 256, 0, stream>>>(row, col, cursor, ebuf);

    // casts
    k_xcast<<<(NN * FIN / 4 + 255) / 256, 256, 0, stream>>>(x, hA);
    k_wt<<<(256 * FIN + 255) / 256, 256, 0, stream>>>(Wl[0], Wt[0], FIN);
    for (int l = 1; l < 5; ++l)
        k_wt<<<(256 * HD + 255) / 256, 256, 0, stream>>>(Wl[l], Wt[l], HD);

    int K = FIN;
    for (int l = 0; l < 5; ++l) {
        k_mm<<<(NN + 63) / 64, 256, 0, stream>>>(hA, Wt[l], dinv, Y, K);
        k_gather<<<(NN + 3) / 4, 256, 0, stream>>>(Y, rowptr, ebuf, dinv, bl[l], hA);
        K = HD;
    }

    dim3 poolGrid(NG, HD / 64);
    k_pool<<<poolGrid, 256, 0, stream>>>(hA, gstart, pool);
    k_out<<<NG * NC, 64, 0, stream>>>(pool, Wout, bout, out);
}

// Round 6
// 385.746 us; speedup vs baseline: 15.1282x; 1.0998x over previous
//
#include <hip/hip_runtime.h>

#define NN 20000
#define NE 320000
#define FIN 64
#define HD 256
#define NC 10
#define NG 64

typedef unsigned short u16;
typedef unsigned int u32;
typedef __attribute__((ext_vector_type(8))) short short8;   // 8 bf16 (4 VGPRs)
typedef __attribute__((ext_vector_type(4))) float f32x4;    // 4 fp32 acc

__device__ __forceinline__ float bf2f(u16 u) {
    union { u32 i; float f; } v; v.i = ((u32)u) << 16; return v.f;
}
__device__ __forceinline__ u16 f2bf(float f) {
    union { float f; u32 i; } v; v.f = f;
    u32 r = v.i + 0x7fffu + ((v.i >> 16) & 1u);   // RNE
    return (u16)(r >> 16);
}

// ---------------- prep: degi=0, gstart=NN, xcast ----------------
__global__ void k_prep(const float* __restrict__ x, u16* __restrict__ hx,
                       int* __restrict__ degi, int* __restrict__ gstart) {
    int i = blockIdx.x * 256 + threadIdx.x;
    if (i < NN) degi[i] = 0;
    if (i < NG) gstart[i] = NN;
    if (i < NN * FIN / 4) {
        float4 v = *(const float4*)&x[(size_t)i * 4];
        u32 lo = (u32)f2bf(v.x) | ((u32)f2bf(v.y) << 16);
        u32 hi = (u32)f2bf(v.z) | ((u32)f2bf(v.w) << 16);
        *(uint2*)&hx[(size_t)i * 4] = make_uint2(lo, hi);
    }
}

// ---------------- degree count + graph bounds ----------------
__global__ void k_deg(const int* __restrict__ col, int* __restrict__ degi,
                      const int* __restrict__ batch, int* __restrict__ gstart) {
    int i = blockIdx.x * 256 + threadIdx.x;
    if (i < NE) atomicAdd(&degi[col[i]], 1);
    if (i < NN) {
        int b = batch[i];
        int prev = (i == 0) ? -1 : batch[i - 1];
        if (b != prev) gstart[b] = i;
    }
}

// ---------------- single-block exclusive scan -> rowptr, cursor; dinv -----
__global__ __launch_bounds__(1024) void k_scan(const int* __restrict__ degi,
                                               int* __restrict__ rowptr,
                                               int* __restrict__ cursor,
                                               float* __restrict__ dinv) {
    __shared__ int wsum[16];
    __shared__ int carry;
    if (threadIdx.x == 0) carry = 0;
    __syncthreads();
    const int lane = threadIdx.x & 63;
    const int wid = threadIdx.x >> 6;
    for (int base = 0; base < NN; base += 1024) {
        int i = base + threadIdx.x;
        int v = (i < NN) ? degi[i] : 0;
        int x = v;
#pragma unroll
        for (int off = 1; off < 64; off <<= 1) {
            int y = __shfl_up(x, off);
            if (lane >= off) x += y;
        }
        if (lane == 63) wsum[wid] = x;
        __syncthreads();
        int woff = 0;
        for (int w = 0; w < wid; ++w) woff += wsum[w];
        int excl = carry + woff + x - v;
        if (i < NN) {
            rowptr[i] = excl;
            cursor[i] = excl;
            dinv[i] = rsqrtf((float)(1 + v));
        }
        __syncthreads();
        if (threadIdx.x == 0) {
            int tot = 0;
            for (int w = 0; w < 16; ++w) tot += wsum[w];
            carry += tot;
        }
        __syncthreads();
    }
    if (threadIdx.x == 0) rowptr[NN] = carry;
}

// ---------------- fill CSR buckets ----------------
__global__ void k_fill(const int* __restrict__ row, const int* __restrict__ col,
                       int* __restrict__ cursor, int* __restrict__ ebuf) {
    int e = blockIdx.x * 256 + threadIdx.x;
    if (e < NE) {
        int c = col[e];
        int pos = atomicAdd(&cursor[c], 1);
        ebuf[pos] = row[e];
    }
}

// ---------------- LDS-tiled transpose+cast of all 5 W: [K][256]f32 -> [256][K]bf16
__global__ __launch_bounds__(256) void k_trans(const float* __restrict__ W0, const float* __restrict__ W1,
                                               const float* __restrict__ W2, const float* __restrict__ W3,
                                               const float* __restrict__ W4,
                                               u16* __restrict__ T0, u16* __restrict__ T1,
                                               u16* __restrict__ T2, u16* __restrict__ T3,
                                               u16* __restrict__ T4) {
    int l = blockIdx.z;
    const float* W = (l == 0) ? W0 : (l == 1) ? W1 : (l == 2) ? W2 : (l == 3) ? W3 : W4;
    u16* T = (l == 0) ? T0 : (l == 1) ? T1 : (l == 2) ? T2 : (l == 3) ? T3 : T4;
    int K = (l == 0) ? FIN : HD;
    int k0 = blockIdx.x * 32;
    if (k0 >= K) return;
    int n0 = blockIdx.y * 32;
    __shared__ float tile[32][33];
    int tx = threadIdx.x & 31, ty = threadIdx.x >> 5;   // 32 x 8
#pragma unroll
    for (int r = 0; r < 32; r += 8)
        tile[ty + r][tx] = W[(size_t)(k0 + ty + r) * HD + n0 + tx];
    __syncthreads();
#pragma unroll
    for (int r = 0; r < 32; r += 8)
        T[(size_t)(n0 + ty + r) * K + k0 + tx] = f2bf(tile[tx][ty + r]);
}

// ---------------- MFMA matmul: Y[m][n] = bf16(dinv[m] * (A @ Wt^T)[m][n]) --
__global__ __launch_bounds__(256) void k_mm(const u16* __restrict__ A,
                                            const u16* __restrict__ Wt,
                                            const float* __restrict__ dinv,
                                            u16* __restrict__ Y,
                                            int K) {
    __shared__ u16 Asm[64][40];
    __shared__ u16 Bsm[256][40];
    const int m0 = blockIdx.x * 64;
    const int t = threadIdx.x;
    const int wave = t >> 6;
    const int lane = t & 63;
    const int quad = lane >> 4;
    const int l16 = lane & 15;
    const int n0 = wave * 64;

    f32x4 acc[4][4];
#pragma unroll
    for (int i = 0; i < 4; ++i)
#pragma unroll
        for (int j = 0; j < 4; ++j) acc[i][j] = (f32x4){0.f, 0.f, 0.f, 0.f};

    for (int k0 = 0; k0 < K; k0 += 32) {
        {
            int row = t >> 2, seg = t & 3;
            int gm = m0 + row;
            float4 v = make_float4(0.f, 0.f, 0.f, 0.f);
            if (gm < NN) v = *(const float4*)&A[(size_t)gm * K + k0 + seg * 8];
            *(float4*)&Asm[row][seg * 8] = v;
        }
        {
#pragma unroll
            for (int j = 0; j < 4; ++j) {
                float4 v = *(const float4*)&Wt[(size_t)t * K + k0 + j * 8];
                *(float4*)&Bsm[t][j * 8] = v;
            }
        }
        __syncthreads();
        short8 a[4], b[4];
#pragma unroll
        for (int i = 0; i < 4; ++i) a[i] = *(const short8*)&Asm[i * 16 + l16][quad * 8];
#pragma unroll
        for (int j = 0; j < 4; ++j) b[j] = *(const short8*)&Bsm[n0 + j * 16 + l16][quad * 8];
#pragma unroll
        for (int i = 0; i < 4; ++i)
#pragma unroll
            for (int j = 0; j < 4; ++j)
                acc[i][j] = __builtin_amdgcn_mfma_f32_16x16x32_bf16(a[i], b[j], acc[i][j], 0, 0, 0);
        __syncthreads();
    }
#pragma unroll
    for (int i = 0; i < 4; ++i) {
#pragma unroll
        for (int r = 0; r < 4; ++r) {
            int m = m0 + i * 16 + quad * 4 + r;
            if (m >= NN) continue;
            float d = dinv[m];
#pragma unroll
            for (int j = 0; j < 4; ++j) {
                int n = n0 + j * 16 + l16;
                Y[(size_t)m * HD + n] = f2bf(acc[i][j][r] * d);
            }
        }
    }
}

// ---------------- gather v2: two 32-lane halves, uint4 loads, 4 edges in flight
__global__ __launch_bounds__(256) void k_gather(const u16* __restrict__ Y,
                                                const int* __restrict__ rowptr,
                                                const int* __restrict__ ebuf,
                                                const float* __restrict__ dinv,
                                                const float* __restrict__ b,
                                                u16* __restrict__ h) {
    int n = blockIdx.x * 4 + (threadIdx.x >> 6);
    if (n >= NN) return;
    int lane = threadIdx.x & 63;
    int half = lane >> 5;
    int seg = lane & 31;           // 16-B segment: features seg*8 .. seg*8+7
    int s = rowptr[n], e = rowptr[n + 1];
    float acc[8];
    if (half == 0) {               // self-loop
        uint4 v = *(const uint4*)&Y[(size_t)n * HD + seg * 8];
        acc[0] = bf2f((u16)(v.x & 0xffff)); acc[1] = bf2f((u16)(v.x >> 16));
        acc[2] = bf2f((u16)(v.y & 0xffff)); acc[3] = bf2f((u16)(v.y >> 16));
        acc[4] = bf2f((u16)(v.z & 0xffff)); acc[5] = bf2f((u16)(v.z >> 16));
        acc[6] = bf2f((u16)(v.w & 0xffff)); acc[7] = bf2f((u16)(v.w >> 16));
    } else {
#pragma unroll
        for (int k = 0; k < 8; ++k) acc[k] = 0.f;
    }
    int j = s;
    for (; j + 4 <= e; j += 4) {
        int r0 = ebuf[j + half];
        int r1 = ebuf[j + 2 + half];
        uint4 v0 = *(const uint4*)&Y[(size_t)r0 * HD + seg * 8];
        uint4 v1 = *(const uint4*)&Y[(size_t)r1 * HD + seg * 8];
        acc[0] += bf2f((u16)(v0.x & 0xffff)); acc[1] += bf2f((u16)(v0.x >> 16));
        acc[2] += bf2f((u16)(v0.y & 0xffff)); acc[3] += bf2f((u16)(v0.y >> 16));
        acc[4] += bf2f((u16)(v0.z & 0xffff)); acc[5] += bf2f((u16)(v0.z >> 16));
        acc[6] += bf2f((u16)(v0.w & 0xffff)); acc[7] += bf2f((u16)(v0.w >> 16));
        acc[0] += bf2f((u16)(v1.x & 0xffff)); acc[1] += bf2f((u16)(v1.x >> 16));
        acc[2] += bf2f((u16)(v1.y & 0xffff)); acc[3] += bf2f((u16)(v1.y >> 16));
        acc[4] += bf2f((u16)(v1.z & 0xffff)); acc[5] += bf2f((u16)(v1.z >> 16));
        acc[6] += bf2f((u16)(v1.w & 0xffff)); acc[7] += bf2f((u16)(v1.w >> 16));
    }
    for (; j < e; j += 2) {
        int idx = j + half;
        if (idx < e) {
            int r = ebuf[idx];
            uint4 v = *(const uint4*)&Y[(size_t)r * HD + seg * 8];
            acc[0] += bf2f((u16)(v.x & 0xffff)); acc[1] += bf2f((u16)(v.x >> 16));
            acc[2] += bf2f((u16)(v.y & 0xffff)); acc[3] += bf2f((u16)(v.y >> 16));
            acc[4] += bf2f((u16)(v.z & 0xffff)); acc[5] += bf2f((u16)(v.z >> 16));
            acc[6] += bf2f((u16)(v.w & 0xffff)); acc[7] += bf2f((u16)(v.w >> 16));
        }
    }
#pragma unroll
    for (int k = 0; k < 8; ++k) acc[k] += __shfl_xor(acc[k], 32);
    if (half == 0) {
        float d = dinv[n];
        float4 b0 = *(const float4*)&b[seg * 8];
        float4 b1 = *(const float4*)&b[seg * 8 + 4];
        float r0 = fmaxf(fmaf(acc[0], d, b0.x), 0.f);
        float r1 = fmaxf(fmaf(acc[1], d, b0.y), 0.f);
        float r2 = fmaxf(fmaf(acc[2], d, b0.z), 0.f);
        float r3 = fmaxf(fmaf(acc[3], d, b0.w), 0.f);
        float r4 = fmaxf(fmaf(acc[4], d, b1.x), 0.f);
        float r5 = fmaxf(fmaf(acc[5], d, b1.y), 0.f);
        float r6 = fmaxf(fmaf(acc[6], d, b1.z), 0.f);
        float r7 = fmaxf(fmaf(acc[7], d, b1.w), 0.f);
        uint4 o;
        o.x = (u32)f2bf(r0) | ((u32)f2bf(r1) << 16);
        o.y = (u32)f2bf(r2) | ((u32)f2bf(r3) << 16);
        o.z = (u32)f2bf(r4) | ((u32)f2bf(r5) << 16);
        o.w = (u32)f2bf(r6) | ((u32)f2bf(r7) << 16);
        *(uint4*)&h[(size_t)n * HD + seg * 8] = o;
    }
}

// ---------------- fused pool + head: one block per graph -------------------
__global__ __launch_bounds__(256) void k_poolout(const u16* __restrict__ h,
                                                 const int* __restrict__ gstart,
                                                 const float* __restrict__ Wout,
                                                 const float* __restrict__ bout,
                                                 float* __restrict__ out) {
    int g = blockIdx.x;
    int t = threadIdx.x;                 // one thread per feature
    __shared__ float pooled[HD];
    __shared__ float part[NC][16];
    __shared__ int s_se[2];
    if (t == 0) {
        int st = gstart[g];
        int en = NN;
        for (int gg = g + 1; gg < NG; ++gg) en = min(en, gstart[gg]);
        s_se[0] = st; s_se[1] = en;
    }
    __syncthreads();
    int st = s_se[0], en = s_se[1];
    float a0 = 0.f, a1 = 0.f, a2 = 0.f, a3 = 0.f;
    int n = st;
    for (; n + 4 <= en; n += 4) {
        a0 += bf2f(h[(size_t)n * HD + t]);
        a1 += bf2f(h[(size_t)(n + 1) * HD + t]);
        a2 += bf2f(h[(size_t)(n + 2) * HD + t]);
        a3 += bf2f(h[(size_t)(n + 3) * HD + t]);
    }
    for (; n < en; ++n) a0 += bf2f(h[(size_t)n * HD + t]);
    float inv = 1.0f / (float)max(en - st, 1);
    pooled[t] = (a0 + a1 + a2 + a3) * inv;
    __syncthreads();
    // head: 10 classes x 16 partial lanes
    if (t < NC * 16) {
        int c = t >> 4, l16 = t & 15;
        float s = 0.f;
        for (int f = l16; f < HD; f += 16)
            s = fmaf(pooled[f], Wout[(size_t)f * NC + c], s);
        part[c][l16] = s;
    }
    __syncthreads();
    if (t < NC) {
        float s = 0.f;
#pragma unroll
        for (int k = 0; k < 16; ++k) s += part[t][k];
        out[(size_t)g * NC + t] = s + bout[t];
    }
}

extern "C" void kernel_launch(void* const* d_in, const int* in_sizes, int n_in,
                              void* d_out, int out_size, void* d_ws, size_t ws_size,
                              hipStream_t stream) {
    const float* x     = (const float*)d_in[0];
    const int*   ei    = (const int*)d_in[1];
    const int*   batch = (const int*)d_in[2];
    const float* Wl[5] = {(const float*)d_in[3], (const float*)d_in[5], (const float*)d_in[7],
                          (const float*)d_in[9], (const float*)d_in[11]};
    const float* bl[5] = {(const float*)d_in[4], (const float*)d_in[6], (const float*)d_in[8],
                          (const float*)d_in[10], (const float*)d_in[12]};
    const float* Wout = (const float*)d_in[13];
    const float* bout = (const float*)d_in[14];
    float* out = (float*)d_out;

    const int* row = ei;
    const int* col = ei + NE;

    char* p = (char*)d_ws;
    auto take = [&](size_t bytes) { char* q = p; p += (bytes + 255) & ~(size_t)255; return q; };
    float* dinv   = (float*)take(NN * 4);
    int*   degi   = (int*)take(NN * 4);
    int*   rowptr = (int*)take((NN + 1) * 4);
    int*   cursor = (int*)take(NN * 4);
    int*   ebuf   = (int*)take(NE * 4);
    int*   gstart = (int*)take(NG * 4);
    u16*   Wt[5];
    for (int l = 0; l < 5; ++l) Wt[l] = (u16*)take((size_t)HD * HD * 2);
    u16*   hA     = (u16*)take((size_t)NN * HD * 2);
    u16*   Y      = (u16*)take((size_t)NN * HD * 2);

    k_prep<<<(NN * FIN / 4 + 255) / 256, 256, 0, stream>>>(x, hA, degi, gstart);
    k_deg<<<(NE + 255) / 256, 256, 0, stream>>>(col, degi, batch, gstart);
    k_scan<<<1, 1024, 0, stream>>>(degi, rowptr, cursor, dinv);
    k_fill<<<(NE + 255) / 256, 256, 0, stream>>>(row, col, cursor, ebuf);
    dim3 tGrid(8, 8, 5);
    k_trans<<<tGrid, 256, 0, stream>>>(Wl[0], Wl[1], Wl[2], Wl[3], Wl[4],
                                       Wt[0], Wt[1], Wt[2], Wt[3], Wt[4]);

    int K = FIN;
    for (int l = 0; l < 5; ++l) {
        k_mm<<<(NN + 63) / 64, 256, 0, stream>>>(hA, Wt[l], dinv, Y, K);
        k_gather<<<(NN + 3) / 4, 256, 0, stream>>>(Y, rowptr, ebuf, dinv, bl[l], hA);
        K = HD;
    }

    k_poolout<<<NG, 256, 0, stream>>>(hA, gstart, Wout, bout, out);
}

// Round 7
// 363.166 us; speedup vs baseline: 16.0688x; 1.0622x over previous
//
#include <hip/hip_runtime.h>

#define NN 20000
#define NE 320000
#define FIN 64
#define HD 256
#define NC 10
#define NG 64
#define NB ((NN + 255) / 256)   // 79 scan blocks

typedef unsigned short u16;
typedef unsigned int u32;
typedef __attribute__((ext_vector_type(8))) short short8;   // 8 bf16 (4 VGPRs)
typedef __attribute__((ext_vector_type(4))) float f32x4;    // 4 fp32 acc

__device__ __forceinline__ float bf2f(u16 u) {
    union { u32 i; float f; } v; v.i = ((u32)u) << 16; return v.f;
}
__device__ __forceinline__ u16 f2bf(float f) {
    union { float f; u32 i; } v; v.f = f;
    u32 r = v.i + 0x7fffu + ((v.i >> 16) & 1u);   // RNE
    return (u16)(r >> 16);
}

// ---------------- prep: degi=0, gstart=NN ----------------
__global__ void k_prep(int* __restrict__ degi, int* __restrict__ gstart) {
    int i = blockIdx.x * 256 + threadIdx.x;
    if (i < NN) degi[i] = 0;
    if (i < NG) gstart[i] = NN;
}

// ---------------- degree count + graph bounds ----------------
__global__ void k_deg(const int* __restrict__ col, int* __restrict__ degi,
                      const int* __restrict__ batch, int* __restrict__ gstart) {
    int i = blockIdx.x * 256 + threadIdx.x;
    if (i < NE) atomicAdd(&degi[col[i]], 1);
    if (i < NN) {
        int b = batch[i];
        int prev = (i == 0) ? -1 : batch[i - 1];
        if (b != prev) gstart[b] = i;
    }
}

// ---------------- scan stage 1: per-block exclusive scan + block sums -----
__global__ __launch_bounds__(256) void k_scan1(const int* __restrict__ degi,
                                               int* __restrict__ rowptr,
                                               int* __restrict__ bsum) {
    int t = threadIdx.x;
    int i = blockIdx.x * 256 + t;
    int v = (i < NN) ? degi[i] : 0;
    int lane = t & 63, wid = t >> 6;
    int x = v;
#pragma unroll
    for (int off = 1; off < 64; off <<= 1) {
        int y = __shfl_up(x, off);
        if (lane >= off) x += y;
    }
    __shared__ int ws[4];
    if (lane == 63) ws[wid] = x;
    __syncthreads();
    int woff = 0;
    for (int w = 0; w < wid; ++w) woff += ws[w];
    if (i < NN) rowptr[i] = woff + x - v;       // block-local exclusive
    if (t == 255) bsum[blockIdx.x] = woff + x;  // block total
}

// ---------------- scan stage 2: exclusive scan of NB block sums -----------
__global__ __launch_bounds__(128) void k_scan2(int* __restrict__ bsum, int* __restrict__ rowptr) {
    __shared__ int s[NB + 1];
    int t = threadIdx.x;
    if (t < NB) s[t] = bsum[t];
    __syncthreads();
    if (t == 0) {
        int run = 0;
        for (int k = 0; k < NB; ++k) { int tmp = s[k]; s[k] = run; run += tmp; }
        s[NB] = run;
    }
    __syncthreads();
    if (t < NB) bsum[t] = s[t];
    if (t == 0) rowptr[NN] = s[NB];
}

// ---------------- scan stage 3: fixup + cursor + dinv + u0 = bf16(dinv*x) -
__global__ void k_scan3(const int* __restrict__ degi, const int* __restrict__ bsum,
                        int* __restrict__ rowptr, int* __restrict__ cursor,
                        float* __restrict__ dinv,
                        const float* __restrict__ x, u16* __restrict__ u0) {
    int i = blockIdx.x * 256 + threadIdx.x;
    if (i < NN) {
        int rp = rowptr[i] + bsum[i >> 8];
        rowptr[i] = rp;
        cursor[i] = rp;
        dinv[i] = rsqrtf((float)(1 + degi[i]));
    }
    if (i < NN * FIN / 4) {
        int node = i >> 4;                       // 16 float4 per node
        float d = rsqrtf((float)(1 + degi[node]));
        float4 v = *(const float4*)&x[(size_t)i * 4];
        u32 lo = (u32)f2bf(v.x * d) | ((u32)f2bf(v.y * d) << 16);
        u32 hi = (u32)f2bf(v.z * d) | ((u32)f2bf(v.w * d) << 16);
        *(uint2*)&u0[(size_t)i * 4] = make_uint2(lo, hi);
    }
}

// ---------------- fill CSR buckets ----------------
__global__ void k_fill(const int* __restrict__ row, const int* __restrict__ col,
                       int* __restrict__ cursor, int* __restrict__ ebuf) {
    int e = blockIdx.x * 256 + threadIdx.x;
    if (e < NE) {
        int c = col[e];
        int pos = atomicAdd(&cursor[c], 1);
        ebuf[pos] = row[e];
    }
}

// ---------------- LDS-tiled transpose+cast of all 5 W ----------------
__global__ __launch_bounds__(256) void k_trans(const float* __restrict__ W0, const float* __restrict__ W1,
                                               const float* __restrict__ W2, const float* __restrict__ W3,
                                               const float* __restrict__ W4,
                                               u16* __restrict__ T0, u16* __restrict__ T1,
                                               u16* __restrict__ T2, u16* __restrict__ T3,
                                               u16* __restrict__ T4) {
    int l = blockIdx.z;
    const float* W = (l == 0) ? W0 : (l == 1) ? W1 : (l == 2) ? W2 : (l == 3) ? W3 : W4;
    u16* T = (l == 0) ? T0 : (l == 1) ? T1 : (l == 2) ? T2 : (l == 3) ? T3 : T4;
    int K = (l == 0) ? FIN : HD;
    int k0 = blockIdx.x * 32;
    if (k0 >= K) return;
    int n0 = blockIdx.y * 32;
    __shared__ float tile[32][33];
    int tx = threadIdx.x & 31, ty = threadIdx.x >> 5;
#pragma unroll
    for (int r = 0; r < 32; r += 8)
        tile[ty + r][tx] = W[(size_t)(k0 + ty + r) * HD + n0 + tx];
    __syncthreads();
#pragma unroll
    for (int r = 0; r < 32; r += 8)
        T[(size_t)(n0 + ty + r) * K + k0 + tx] = f2bf(tile[tx][ty + r]);
}

// ---------------- gather 256-wide: Z[n] = bf16(dinv[n]*(U[n]+sum U[r])) ----
// U rows pre-scaled by dinv. Two 32-lane halves; 8 edge ids broadcast/batch.
__global__ __launch_bounds__(256) void k_gather256(const u16* __restrict__ U,
                                                   const int* __restrict__ rowptr,
                                                   const int* __restrict__ ebuf,
                                                   const float* __restrict__ dinv,
                                                   u16* __restrict__ Z) {
    int n = blockIdx.x * 4 + (threadIdx.x >> 6);
    if (n >= NN) return;
    int lane = threadIdx.x & 63;
    int half = lane >> 5;
    int seg = lane & 31;
    int s = rowptr[n], e = rowptr[n + 1];
    float acc[8];
    if (half == 0) {
        uint4 v = *(const uint4*)&U[(size_t)n * HD + seg * 8];
        acc[0] = bf2f((u16)(v.x & 0xffff)); acc[1] = bf2f((u16)(v.x >> 16));
        acc[2] = bf2f((u16)(v.y & 0xffff)); acc[3] = bf2f((u16)(v.y >> 16));
        acc[4] = bf2f((u16)(v.z & 0xffff)); acc[5] = bf2f((u16)(v.z >> 16));
        acc[6] = bf2f((u16)(v.w & 0xffff)); acc[7] = bf2f((u16)(v.w >> 16));
    } else {
#pragma unroll
        for (int k = 0; k < 8; ++k) acc[k] = 0.f;
    }
    for (int j = s; j < e; j += 16) {           // 16 edges/iter: 8 per half
        int idx = j + half * 8 + (lane & 7);
        int myid = (idx < e) ? ebuf[idx] : -1;
#pragma unroll
        for (int k = 0; k < 8; ++k) {
            int r = __shfl(myid, (lane & 32) | k);
            int rr = max(r, 0);
            uint4 v = *(const uint4*)&U[(size_t)rr * HD + seg * 8];
            if (r >= 0) {
                acc[0] += bf2f((u16)(v.x & 0xffff)); acc[1] += bf2f((u16)(v.x >> 16));
                acc[2] += bf2f((u16)(v.y & 0xffff)); acc[3] += bf2f((u16)(v.y >> 16));
                acc[4] += bf2f((u16)(v.z & 0xffff)); acc[5] += bf2f((u16)(v.z >> 16));
                acc[6] += bf2f((u16)(v.w & 0xffff)); acc[7] += bf2f((u16)(v.w >> 16));
            }
        }
    }
#pragma unroll
    for (int k = 0; k < 8; ++k) acc[k] += __shfl_xor(acc[k], 32);
    if (half == 0) {
        float d = dinv[n];
        uint4 o;
        o.x = (u32)f2bf(acc[0] * d) | ((u32)f2bf(acc[1] * d) << 16);
        o.y = (u32)f2bf(acc[2] * d) | ((u32)f2bf(acc[3] * d) << 16);
        o.z = (u32)f2bf(acc[4] * d) | ((u32)f2bf(acc[5] * d) << 16);
        o.w = (u32)f2bf(acc[6] * d) | ((u32)f2bf(acc[7] * d) << 16);
        *(uint4*)&Z[(size_t)n * HD + seg * 8] = o;
    }
}

// ---------------- gather 64-wide (layer 1): 8 groups x 8 lanes -------------
__global__ __launch_bounds__(256) void k_gather64(const u16* __restrict__ U,
                                                  const int* __restrict__ rowptr,
                                                  const int* __restrict__ ebuf,
                                                  const float* __restrict__ dinv,
                                                  u16* __restrict__ Z) {
    int n = blockIdx.x * 4 + (threadIdx.x >> 6);
    if (n >= NN) return;
    int lane = threadIdx.x & 63;
    int grp = lane >> 3;            // 0..7 : edge within batch
    int seg = lane & 7;             // 16-B feature segment (8 x 8 bf16 = 64)
    int s = rowptr[n], e = rowptr[n + 1];
    float acc[8];
    if (grp == 0) {
        uint4 v = *(const uint4*)&U[(size_t)n * FIN + seg * 8];
        acc[0] = bf2f((u16)(v.x & 0xffff)); acc[1] = bf2f((u16)(v.x >> 16));
        acc[2] = bf2f((u16)(v.y & 0xffff)); acc[3] = bf2f((u16)(v.y >> 16));
        acc[4] = bf2f((u16)(v.z & 0xffff)); acc[5] = bf2f((u16)(v.z >> 16));
        acc[6] = bf2f((u16)(v.w & 0xffff)); acc[7] = bf2f((u16)(v.w >> 16));
    } else {
#pragma unroll
        for (int k = 0; k < 8; ++k) acc[k] = 0.f;
    }
    for (int j = s; j < e; j += 8) {
        int idx = j + grp;
        int r = (idx < e) ? ebuf[idx] : -1;
        int rr = max(r, 0);
        uint4 v = *(const uint4*)&U[(size_t)rr * FIN + seg * 8];
        if (r >= 0) {
            acc[0] += bf2f((u16)(v.x & 0xffff)); acc[1] += bf2f((u16)(v.x >> 16));
            acc[2] += bf2f((u16)(v.y & 0xffff)); acc[3] += bf2f((u16)(v.y >> 16));
            acc[4] += bf2f((u16)(v.z & 0xffff)); acc[5] += bf2f((u16)(v.z >> 16));
            acc[6] += bf2f((u16)(v.w & 0xffff)); acc[7] += bf2f((u16)(v.w >> 16));
        }
    }
#pragma unroll
    for (int off = 8; off < 64; off <<= 1)
#pragma unroll
        for (int k = 0; k < 8; ++k) acc[k] += __shfl_xor(acc[k], off);
    if (grp == 0) {
        float d = dinv[n];
        uint4 o;
        o.x = (u32)f2bf(acc[0] * d) | ((u32)f2bf(acc[1] * d) << 16);
        o.y = (u32)f2bf(acc[2] * d) | ((u32)f2bf(acc[3] * d) << 16);
        o.z = (u32)f2bf(acc[4] * d) | ((u32)f2bf(acc[5] * d) << 16);
        o.w = (u32)f2bf(acc[6] * d) | ((u32)f2bf(acc[7] * d) << 16);
        *(uint4*)&Z[(size_t)n * FIN + seg * 8] = o;
    }
}

// ---------------- MFMA matmul: O = [dinv *] relu(Z @ Wt^T + b) -------------
__global__ __launch_bounds__(256) void k_mm(const u16* __restrict__ A,
                                            const u16* __restrict__ Wt,
                                            const float* __restrict__ bias,
                                            const float* __restrict__ dinv,
                                            u16* __restrict__ O,
                                            int K, int scaleOut) {
    __shared__ u16 Asm[64][40];
    __shared__ u16 Bsm[256][40];
    __shared__ float bs[HD];
    const int m0 = blockIdx.x * 64;
    const int t = threadIdx.x;
    const int wave = t >> 6;
    const int lane = t & 63;
    const int quad = lane >> 4;
    const int l16 = lane & 15;
    const int n0 = wave * 64;
    bs[t] = bias[t];

    f32x4 acc[4][4];
#pragma unroll
    for (int i = 0; i < 4; ++i)
#pragma unroll
        for (int j = 0; j < 4; ++j) acc[i][j] = (f32x4){0.f, 0.f, 0.f, 0.f};

    for (int k0 = 0; k0 < K; k0 += 32) {
        {
            int row = t >> 2, seg = t & 3;
            int gm = m0 + row;
            float4 v = make_float4(0.f, 0.f, 0.f, 0.f);
            if (gm < NN) v = *(const float4*)&A[(size_t)gm * K + k0 + seg * 8];
            *(float4*)&Asm[row][seg * 8] = v;
        }
        {
#pragma unroll
            for (int j = 0; j < 4; ++j) {
                float4 v = *(const float4*)&Wt[(size_t)t * K + k0 + j * 8];
                *(float4*)&Bsm[t][j * 8] = v;
            }
        }
        __syncthreads();
        short8 a[4], b[4];
#pragma unroll
        for (int i = 0; i < 4; ++i) a[i] = *(const short8*)&Asm[i * 16 + l16][quad * 8];
#pragma unroll
        for (int j = 0; j < 4; ++j) b[j] = *(const short8*)&Bsm[n0 + j * 16 + l16][quad * 8];
#pragma unroll
        for (int i = 0; i < 4; ++i)
#pragma unroll
            for (int j = 0; j < 4; ++j)
                acc[i][j] = __builtin_amdgcn_mfma_f32_16x16x32_bf16(a[i], b[j], acc[i][j], 0, 0, 0);
        __syncthreads();
    }
#pragma unroll
    for (int i = 0; i < 4; ++i) {
#pragma unroll
        for (int r = 0; r < 4; ++r) {
            int m = m0 + i * 16 + quad * 4 + r;
            if (m >= NN) continue;
            float d = scaleOut ? dinv[m] : 1.0f;
#pragma unroll
            for (int j = 0; j < 4; ++j) {
                int n = n0 + j * 16 + l16;
                float val = fmaxf(acc[i][j][r] + bs[n], 0.f) * d;
                O[(size_t)m * HD + n] = f2bf(val);
            }
        }
    }
}

// ---------------- fused pool + head ----------------
__global__ __launch_bounds__(256) void k_poolout(const u16* __restrict__ h,
                                                 const int* __restrict__ gstart,
                                                 const float* __restrict__ Wout,
                                                 const float* __restrict__ bout,
                                                 float* __restrict__ out) {
    int g = blockIdx.x;
    int t = threadIdx.x;
    __shared__ float pooled[HD];
    __shared__ float part[NC][16];
    __shared__ int s_se[2];
    if (t == 0) {
        int st = gstart[g];
        int en = NN;
        for (int gg = g + 1; gg < NG; ++gg) en = min(en, gstart[gg]);
        s_se[0] = st; s_se[1] = en;
    }
    __syncthreads();
    int st = s_se[0], en = s_se[1];
    float a0 = 0.f, a1 = 0.f, a2 = 0.f, a3 = 0.f;
    int n = st;
    for (; n + 4 <= en; n += 4) {
        a0 += bf2f(h[(size_t)n * HD + t]);
        a1 += bf2f(h[(size_t)(n + 1) * HD + t]);
        a2 += bf2f(h[(size_t)(n + 2) * HD + t]);
        a3 += bf2f(h[(size_t)(n + 3) * HD + t]);
    }
    for (; n < en; ++n) a0 += bf2f(h[(size_t)n * HD + t]);
    float inv = 1.0f / (float)max(en - st, 1);
    pooled[t] = (a0 + a1 + a2 + a3) * inv;
    __syncthreads();
    if (t < NC * 16) {
        int c = t >> 4, l16 = t & 15;
        float s = 0.f;
        for (int f = l16; f < HD; f += 16)
            s = fmaf(pooled[f], Wout[(size_t)f * NC + c], s);
        part[c][l16] = s;
    }
    __syncthreads();
    if (t < NC) {
        float s = 0.f;
#pragma unroll
        for (int k = 0; k < 16; ++k) s += part[t][k];
        out[(size_t)g * NC + t] = s + bout[t];
    }
}

extern "C" void kernel_launch(void* const* d_in, const int* in_sizes, int n_in,
                              void* d_out, int out_size, void* d_ws, size_t ws_size,
                              hipStream_t stream) {
    const float* x     = (const float*)d_in[0];
    const int*   ei    = (const int*)d_in[1];
    const int*   batch = (const int*)d_in[2];
    const float* Wl[5] = {(const float*)d_in[3], (const float*)d_in[5], (const float*)d_in[7],
                          (const float*)d_in[9], (const float*)d_in[11]};
    const float* bl[5] = {(const float*)d_in[4], (const float*)d_in[6], (const float*)d_in[8],
                          (const float*)d_in[10], (const float*)d_in[12]};
    const float* Wout = (const float*)d_in[13];
    const float* bout = (const float*)d_in[14];
    float* out = (float*)d_out;

    const int* row = ei;
    const int* col = ei + NE;

    char* p = (char*)d_ws;
    auto take = [&](size_t bytes) { char* q = p; p += (bytes + 255) & ~(size_t)255; return q; };
    float* dinv   = (float*)take(NN * 4);
    int*   degi   = (int*)take(NN * 4);
    int*   rowptr = (int*)take((NN + 1) * 4);
    int*   cursor = (int*)take(NN * 4);
    int*   bsum   = (int*)take(NB * 4);
    int*   ebuf   = (int*)take(NE * 4);
    int*   gstart = (int*)take(NG * 4);
    u16*   Wt[5];
    for (int l = 0; l < 5; ++l) Wt[l] = (u16*)take((size_t)HD * HD * 2);
    u16*   B1     = (u16*)take((size_t)NN * HD * 2);   // activations (dinv-scaled, except last)
    u16*   B2     = (u16*)take((size_t)NN * HD * 2);   // aggregated z

    k_prep<<<NB, 256, 0, stream>>>(degi, gstart);
    k_deg<<<(NE + 255) / 256, 256, 0, stream>>>(col, degi, batch, gstart);
    k_scan1<<<NB, 256, 0, stream>>>(degi, rowptr, bsum);
    k_scan2<<<1, 128, 0, stream>>>(bsum, rowptr);
    k_scan3<<<(NN * FIN / 4 + 255) / 256, 256, 0, stream>>>(degi, bsum, rowptr, cursor, dinv, x, B1);
    k_fill<<<(NE + 255) / 256, 256, 0, stream>>>(row, col, cursor, ebuf);
    dim3 tGrid(8, 8, 5);
    k_trans<<<tGrid, 256, 0, stream>>>(Wl[0], Wl[1], Wl[2], Wl[3], Wl[4],
                                       Wt[0], Wt[1], Wt[2], Wt[3], Wt[4]);

    // layer 1 (64-wide aggregation first)
    k_gather64<<<(NN + 3) / 4, 256, 0, stream>>>(B1, rowptr, ebuf, dinv, B2);
    k_mm<<<(NN + 63) / 64, 256, 0, stream>>>(B2, Wt[0], bl[0], dinv, B1, FIN, 1);
    // layers 2..5
    for (int l = 1; l < 5; ++l) {
        k_gather256<<<(NN + 3) / 4, 256, 0, stream>>>(B1, rowptr, ebuf, dinv, B2);
        k_mm<<<(NN + 63) / 64, 256, 0, stream>>>(B2, Wt[l], bl[l], dinv, B1, HD, (l < 4) ? 1 : 0);
    }

    k_poolout<<<NG, 256, 0, stream>>>(B1, gstart, Wout, bout, out);
}

// Round 8
// 351.823 us; speedup vs baseline: 16.5869x; 1.0322x over previous
//
#include <hip/hip_runtime.h>

#define NN 20000
#define NE 320000
#define FIN 64
#define HD 256
#define NC 10
#define NG 64
#define NB ((NN + 255) / 256)   // 79 scan blocks

typedef unsigned short u16;
typedef unsigned int u32;
typedef __attribute__((ext_vector_type(8))) short short8;   // 8 bf16 (4 VGPRs)
typedef __attribute__((ext_vector_type(4))) float f32x4;    // 4 fp32 acc

__device__ __forceinline__ float bf2f(u16 u) {
    union { u32 i; float f; } v; v.i = ((u32)u) << 16; return v.f;
}
__device__ __forceinline__ u16 f2bf(float f) {
    union { float f; u32 i; } v; v.f = f;
    u32 r = v.i + 0x7fffu + ((v.i >> 16) & 1u);   // RNE
    return (u16)(r >> 16);
}

// ---------------- prep: degi=0, gstart=NN ----------------
__global__ void k_prep(int* __restrict__ degi, int* __restrict__ gstart) {
    int i = blockIdx.x * 256 + threadIdx.x;
    if (i < NN) degi[i] = 0;
    if (i < NG) gstart[i] = NN;
}

// ---------------- degree count + graph bounds ----------------
__global__ void k_deg(const int* __restrict__ col, int* __restrict__ degi,
                      const int* __restrict__ batch, int* __restrict__ gstart) {
    int i = blockIdx.x * 256 + threadIdx.x;
    if (i < NE) atomicAdd(&degi[col[i]], 1);
    if (i < NN) {
        int b = batch[i];
        int prev = (i == 0) ? -1 : batch[i - 1];
        if (b != prev) gstart[b] = i;
    }
}

// ---------------- scan stage 1: per-block exclusive scan + block sums -----
__global__ __launch_bounds__(256) void k_scan1(const int* __restrict__ degi,
                                               int* __restrict__ rowptr,
                                               int* __restrict__ bsum) {
    int t = threadIdx.x;
    int i = blockIdx.x * 256 + t;
    int v = (i < NN) ? degi[i] : 0;
    int lane = t & 63, wid = t >> 6;
    int x = v;
#pragma unroll
    for (int off = 1; off < 64; off <<= 1) {
        int y = __shfl_up(x, off);
        if (lane >= off) x += y;
    }
    __shared__ int ws[4];
    if (lane == 63) ws[wid] = x;
    __syncthreads();
    int woff = 0;
    for (int w = 0; w < wid; ++w) woff += ws[w];
    if (i < NN) rowptr[i] = woff + x - v;       // block-local exclusive
    if (t == 255) bsum[blockIdx.x] = woff + x;  // block total
}

// ---------------- scan stage 2: exclusive scan of NB block sums -----------
__global__ __launch_bounds__(128) void k_scan2(int* __restrict__ bsum, int* __restrict__ rowptr) {
    __shared__ int s[NB + 1];
    int t = threadIdx.x;
    if (t < NB) s[t] = bsum[t];
    __syncthreads();
    if (t == 0) {
        int run = 0;
        for (int k = 0; k < NB; ++k) { int tmp = s[k]; s[k] = run; run += tmp; }
        s[NB] = run;
    }
    __syncthreads();
    if (t < NB) bsum[t] = s[t];
    if (t == 0) rowptr[NN] = s[NB];
}

// ---------------- scan stage 3: fixup + cursor + dinv + u0 = bf16(dinv*x) -
__global__ void k_scan3(const int* __restrict__ degi, const int* __restrict__ bsum,
                        int* __restrict__ rowptr, int* __restrict__ cursor,
                        float* __restrict__ dinv,
                        const float* __restrict__ x, u16* __restrict__ u0) {
    int i = blockIdx.x * 256 + threadIdx.x;
    if (i < NN) {
        int rp = rowptr[i] + bsum[i >> 8];
        rowptr[i] = rp;
        cursor[i] = rp;
        dinv[i] = rsqrtf((float)(1 + degi[i]));
    }
    if (i < NN * FIN / 4) {
        int node = i >> 4;                       // 16 float4 per node
        float d = rsqrtf((float)(1 + degi[node]));
        float4 v = *(const float4*)&x[(size_t)i * 4];
        u32 lo = (u32)f2bf(v.x * d) | ((u32)f2bf(v.y * d) << 16);
        u32 hi = (u32)f2bf(v.z * d) | ((u32)f2bf(v.w * d) << 16);
        *(uint2*)&u0[(size_t)i * 4] = make_uint2(lo, hi);
    }
}

// ---------------- fill CSR buckets ----------------
__global__ void k_fill(const int* __restrict__ row, const int* __restrict__ col,
                       int* __restrict__ cursor, int* __restrict__ ebuf) {
    int e = blockIdx.x * 256 + threadIdx.x;
    if (e < NE) {
        int c = col[e];
        int pos = atomicAdd(&cursor[c], 1);
        ebuf[pos] = row[e];
    }
}

// ---------------- LDS-tiled transpose+cast of all 5 W ----------------
__global__ __launch_bounds__(256) void k_trans(const float* __restrict__ W0, const float* __restrict__ W1,
                                               const float* __restrict__ W2, const float* __restrict__ W3,
                                               const float* __restrict__ W4,
                                               u16* __restrict__ T0, u16* __restrict__ T1,
                                               u16* __restrict__ T2, u16* __restrict__ T3,
                                               u16* __restrict__ T4) {
    int l = blockIdx.z;
    const float* W = (l == 0) ? W0 : (l == 1) ? W1 : (l == 2) ? W2 : (l == 3) ? W3 : W4;
    u16* T = (l == 0) ? T0 : (l == 1) ? T1 : (l == 2) ? T2 : (l == 3) ? T3 : T4;
    int K = (l == 0) ? FIN : HD;
    int k0 = blockIdx.x * 32;
    if (k0 >= K) return;
    int n0 = blockIdx.y * 32;
    __shared__ float tile[32][33];
    int tx = threadIdx.x & 31, ty = threadIdx.x >> 5;
#pragma unroll
    for (int r = 0; r < 32; r += 8)
        tile[ty + r][tx] = W[(size_t)(k0 + ty + r) * HD + n0 + tx];
    __syncthreads();
#pragma unroll
    for (int r = 0; r < 32; r += 8)
        T[(size_t)(n0 + ty + r) * K + k0 + tx] = f2bf(tile[tx][ty + r]);
}

// ---------------- gather 256-wide v4: 32 edges/iter, 16 loads in flight ----
__global__ __launch_bounds__(256) void k_gather256(const u16* __restrict__ U,
                                                   const int* __restrict__ rowptr,
                                                   const int* __restrict__ ebuf,
                                                   const float* __restrict__ dinv,
                                                   u16* __restrict__ Z) {
    int n = blockIdx.x * 4 + (threadIdx.x >> 6);
    if (n >= NN) return;
    int lane = threadIdx.x & 63;
    int half = lane >> 5;
    int seg = lane & 31;
    int s = rowptr[n], e = rowptr[n + 1];
    float acc[8];
    if (half == 0) {
        uint4 v = *(const uint4*)&U[(size_t)n * HD + seg * 8];
        acc[0] = bf2f((u16)(v.x & 0xffff)); acc[1] = bf2f((u16)(v.x >> 16));
        acc[2] = bf2f((u16)(v.y & 0xffff)); acc[3] = bf2f((u16)(v.y >> 16));
        acc[4] = bf2f((u16)(v.z & 0xffff)); acc[5] = bf2f((u16)(v.z >> 16));
        acc[6] = bf2f((u16)(v.w & 0xffff)); acc[7] = bf2f((u16)(v.w >> 16));
    } else {
#pragma unroll
        for (int k = 0; k < 8; ++k) acc[k] = 0.f;
    }
    for (int j = s; j < e; j += 32) {
        // lanes 0..31 load 32 edge ids coalesced; broadcast via shfl
        int idx = j + lane;
        int myid = (lane < 32 && idx < e) ? ebuf[idx] : -1;
        uint4 v[16];
#pragma unroll
        for (int k = 0; k < 16; ++k) {
            int r = __shfl(myid, 2 * k + half);     // half0: even edges, half1: odd
            uint4 t = *(const uint4*)&U[(size_t)max(r, 0) * HD + seg * 8];
            if (r < 0) t = make_uint4(0u, 0u, 0u, 0u);
            v[k] = t;
        }
#pragma unroll
        for (int k = 0; k < 16; ++k) {
            acc[0] += bf2f((u16)(v[k].x & 0xffff)); acc[1] += bf2f((u16)(v[k].x >> 16));
            acc[2] += bf2f((u16)(v[k].y & 0xffff)); acc[3] += bf2f((u16)(v[k].y >> 16));
            acc[4] += bf2f((u16)(v[k].z & 0xffff)); acc[5] += bf2f((u16)(v[k].z >> 16));
            acc[6] += bf2f((u16)(v[k].w & 0xffff)); acc[7] += bf2f((u16)(v[k].w >> 16));
        }
    }
#pragma unroll
    for (int k = 0; k < 8; ++k) acc[k] += __shfl_xor(acc[k], 32);
    if (half == 0) {
        float d = dinv[n];
        uint4 o;
        o.x = (u32)f2bf(acc[0] * d) | ((u32)f2bf(acc[1] * d) << 16);
        o.y = (u32)f2bf(acc[2] * d) | ((u32)f2bf(acc[3] * d) << 16);
        o.z = (u32)f2bf(acc[4] * d) | ((u32)f2bf(acc[5] * d) << 16);
        o.w = (u32)f2bf(acc[6] * d) | ((u32)f2bf(acc[7] * d) << 16);
        *(uint4*)&Z[(size_t)n * HD + seg * 8] = o;
    }
}

// ---------------- gather 64-wide (layer 1): 16 edges/iter in flight --------
__global__ __launch_bounds__(256) void k_gather64(const u16* __restrict__ U,
                                                  const int* __restrict__ rowptr,
                                                  const int* __restrict__ ebuf,
                                                  const float* __restrict__ dinv,
                                                  u16* __restrict__ Z) {
    int n = blockIdx.x * 4 + (threadIdx.x >> 6);
    if (n >= NN) return;
    int lane = threadIdx.x & 63;
    int grp = lane >> 3;            // 0..7
    int seg = lane & 7;             // 16-B feature segment
    int s = rowptr[n], e = rowptr[n + 1];
    float acc[8];
    if (grp == 0) {
        uint4 v = *(const uint4*)&U[(size_t)n * FIN + seg * 8];
        acc[0] = bf2f((u16)(v.x & 0xffff)); acc[1] = bf2f((u16)(v.x >> 16));
        acc[2] = bf2f((u16)(v.y & 0xffff)); acc[3] = bf2f((u16)(v.y >> 16));
        acc[4] = bf2f((u16)(v.z & 0xffff)); acc[5] = bf2f((u16)(v.z >> 16));
        acc[6] = bf2f((u16)(v.w & 0xffff)); acc[7] = bf2f((u16)(v.w >> 16));
    } else {
#pragma unroll
        for (int k = 0; k < 8; ++k) acc[k] = 0.f;
    }
    for (int j = s; j < e; j += 16) {
        int i0 = j + grp, i1 = j + 8 + grp;
        int r0 = (i0 < e) ? ebuf[i0] : -1;
        int r1 = (i1 < e) ? ebuf[i1] : -1;
        uint4 v0 = *(const uint4*)&U[(size_t)max(r0, 0) * FIN + seg * 8];
        uint4 v1 = *(const uint4*)&U[(size_t)max(r1, 0) * FIN + seg * 8];
        if (r0 < 0) v0 = make_uint4(0u, 0u, 0u, 0u);
        if (r1 < 0) v1 = make_uint4(0u, 0u, 0u, 0u);
        acc[0] += bf2f((u16)(v0.x & 0xffff)); acc[1] += bf2f((u16)(v0.x >> 16));
        acc[2] += bf2f((u16)(v0.y & 0xffff)); acc[3] += bf2f((u16)(v0.y >> 16));
        acc[4] += bf2f((u16)(v0.z & 0xffff)); acc[5] += bf2f((u16)(v0.z >> 16));
        acc[6] += bf2f((u16)(v0.w & 0xffff)); acc[7] += bf2f((u16)(v0.w >> 16));
        acc[0] += bf2f((u16)(v1.x & 0xffff)); acc[1] += bf2f((u16)(v1.x >> 16));
        acc[2] += bf2f((u16)(v1.y & 0xffff)); acc[3] += bf2f((u16)(v1.y >> 16));
        acc[4] += bf2f((u16)(v1.z & 0xffff)); acc[5] += bf2f((u16)(v1.z >> 16));
        acc[6] += bf2f((u16)(v1.w & 0xffff)); acc[7] += bf2f((u16)(v1.w >> 16));
    }
#pragma unroll
    for (int off = 8; off < 64; off <<= 1)
#pragma unroll
        for (int k = 0; k < 8; ++k) acc[k] += __shfl_xor(acc[k], off);
    if (grp == 0) {
        float d = dinv[n];
        uint4 o;
        o.x = (u32)f2bf(acc[0] * d) | ((u32)f2bf(acc[1] * d) << 16);
        o.y = (u32)f2bf(acc[2] * d) | ((u32)f2bf(acc[3] * d) << 16);
        o.z = (u32)f2bf(acc[4] * d) | ((u32)f2bf(acc[5] * d) << 16);
        o.w = (u32)f2bf(acc[6] * d) | ((u32)f2bf(acc[7] * d) << 16);
        *(uint4*)&Z[(size_t)n * FIN + seg * 8] = o;
    }
}

// ---------------- MFMA matmul: O = [dinv *] relu(Z @ Wt^T + b) -------------
__global__ __launch_bounds__(256) void k_mm(const u16* __restrict__ A,
                                            const u16* __restrict__ Wt,
                                            const float* __restrict__ bias,
                                            const float* __restrict__ dinv,
                                            u16* __restrict__ O,
                                            int K, int scaleOut) {
    __shared__ u16 Asm[64][40];
    __shared__ u16 Bsm[256][40];
    __shared__ float bs[HD];
    const int m0 = blockIdx.x * 64;
    const int t = threadIdx.x;
    const int wave = t >> 6;
    const int lane = t & 63;
    const int quad = lane >> 4;
    const int l16 = lane & 15;
    const int n0 = wave * 64;
    bs[t] = bias[t];

    f32x4 acc[4][4];
#pragma unroll
    for (int i = 0; i < 4; ++i)
#pragma unroll
        for (int j = 0; j < 4; ++j) acc[i][j] = (f32x4){0.f, 0.f, 0.f, 0.f};

    for (int k0 = 0; k0 < K; k0 += 32) {
        {
            int row = t >> 2, seg = t & 3;
            int gm = m0 + row;
            float4 v = make_float4(0.f, 0.f, 0.f, 0.f);
            if (gm < NN) v = *(const float4*)&A[(size_t)gm * K + k0 + seg * 8];
            *(float4*)&Asm[row][seg * 8] = v;
        }
        {
#pragma unroll
            for (int j = 0; j < 4; ++j) {
                float4 v = *(const float4*)&Wt[(size_t)t * K + k0 + j * 8];
                *(float4*)&Bsm[t][j * 8] = v;
            }
        }
        __syncthreads();
        short8 a[4], b[4];
#pragma unroll
        for (int i = 0; i < 4; ++i) a[i] = *(const short8*)&Asm[i * 16 + l16][quad * 8];
#pragma unroll
        for (int j = 0; j < 4; ++j) b[j] = *(const short8*)&Bsm[n0 + j * 16 + l16][quad * 8];
#pragma unroll
        for (int i = 0; i < 4; ++i)
#pragma unroll
            for (int j = 0; j < 4; ++j)
                acc[i][j] = __builtin_amdgcn_mfma_f32_16x16x32_bf16(a[i], b[j], acc[i][j], 0, 0, 0);
        __syncthreads();
    }
#pragma unroll
    for (int i = 0; i < 4; ++i) {
#pragma unroll
        for (int r = 0; r < 4; ++r) {
            int m = m0 + i * 16 + quad * 4 + r;
            if (m >= NN) continue;
            float d = scaleOut ? dinv[m] : 1.0f;
#pragma unroll
            for (int j = 0; j < 4; ++j) {
                int n = n0 + j * 16 + l16;
                float val = fmaxf(acc[i][j][r] + bs[n], 0.f) * d;
                O[(size_t)m * HD + n] = f2bf(val);
            }
        }
    }
}

// ---------------- fused pool + head ----------------
__global__ __launch_bounds__(256) void k_poolout(const u16* __restrict__ h,
                                                 const int* __restrict__ gstart,
                                                 const float* __restrict__ Wout,
                                                 const float* __restrict__ bout,
                                                 float* __restrict__ out) {
    int g = blockIdx.x;
    int t = threadIdx.x;
    __shared__ float pooled[HD];
    __shared__ float part[NC][16];
    __shared__ int s_se[2];
    if (t == 0) {
        int st = gstart[g];
        int en = NN;
        for (int gg = g + 1; gg < NG; ++gg) en = min(en, gstart[gg]);
        s_se[0] = st; s_se[1] = en;
    }
    __syncthreads();
    int st = s_se[0], en = s_se[1];
    float a0 = 0.f, a1 = 0.f, a2 = 0.f, a3 = 0.f;
    int n = st;
    for (; n + 4 <= en; n += 4) {
        a0 += bf2f(h[(size_t)n * HD + t]);
        a1 += bf2f(h[(size_t)(n + 1) * HD + t]);
        a2 += bf2f(h[(size_t)(n + 2) * HD + t]);
        a3 += bf2f(h[(size_t)(n + 3) * HD + t]);
    }
    for (; n < en; ++n) a0 += bf2f(h[(size_t)n * HD + t]);
    float inv = 1.0f / (float)max(en - st, 1);
    pooled[t] = (a0 + a1 + a2 + a3) * inv;
    __syncthreads();
    if (t < NC * 16) {
        int c = t >> 4, l16 = t & 15;
        float s = 0.f;
        for (int f = l16; f < HD; f += 16)
            s = fmaf(pooled[f], Wout[(size_t)f * NC + c], s);
        part[c][l16] = s;
    }
    __syncthreads();
    if (t < NC) {
        float s = 0.f;
#pragma unroll
        for (int k = 0; k < 16; ++k) s += part[t][k];
        out[(size_t)g * NC + t] = s + bout[t];
    }
}

extern "C" void kernel_launch(void* const* d_in, const int* in_sizes, int n_in,
                              void* d_out, int out_size, void* d_ws, size_t ws_size,
                              hipStream_t stream) {
    const float* x     = (const float*)d_in[0];
    const int*   ei    = (const int*)d_in[1];
    const int*   batch = (const int*)d_in[2];
    const float* Wl[5] = {(const float*)d_in[3], (const float*)d_in[5], (const float*)d_in[7],
                          (const float*)d_in[9], (const float*)d_in[11]};
    const float* bl[5] = {(const float*)d_in[4], (const float*)d_in[6], (const float*)d_in[8],
                          (const float*)d_in[10], (const float*)d_in[12]};
    const float* Wout = (const float*)d_in[13];
    const float* bout = (const float*)d_in[14];
    float* out = (float*)d_out;

    const int* row = ei;
    const int* col = ei + NE;

    char* p = (char*)d_ws;
    auto take = [&](size_t bytes) { char* q = p; p += (bytes + 255) & ~(size_t)255; return q; };
    float* dinv   = (float*)take(NN * 4);
    int*   degi   = (int*)take(NN * 4);
    int*   rowptr = (int*)take((NN + 1) * 4);
    int*   cursor = (int*)take(NN * 4);
    int*   bsum   = (int*)take(NB * 4);
    int*   ebuf   = (int*)take(NE * 4);
    int*   gstart = (int*)take(NG * 4);
    u16*   Wt[5];
    for (int l = 0; l < 5; ++l) Wt[l] = (u16*)take((size_t)HD * HD * 2);
    u16*   B1     = (u16*)take((size_t)NN * HD * 2);   // activations (dinv-scaled, except last)
    u16*   B2     = (u16*)take((size_t)NN * HD * 2);   // aggregated z

    k_prep<<<NB, 256, 0, stream>>>(degi, gstart);
    k_deg<<<(NE + 255) / 256, 256, 0, stream>>>(col, degi, batch, gstart);
    k_scan1<<<NB, 256, 0, stream>>>(degi, rowptr, bsum);
    k_scan2<<<1, 128, 0, stream>>>(bsum, rowptr);
    k_scan3<<<(NN * FIN / 4 + 255) / 256, 256, 0, stream>>>(degi, bsum, rowptr, cursor, dinv, x, B1);
    k_fill<<<(NE + 255) / 256, 256, 0, stream>>>(row, col, cursor, ebuf);
    dim3 tGrid(8, 8, 5);
    k_trans<<<tGrid, 256, 0, stream>>>(Wl[0], Wl[1], Wl[2], Wl[3], Wl[4],
                                       Wt[0], Wt[1], Wt[2], Wt[3], Wt[4]);

    // layer 1 (64-wide aggregation first)
    k_gather64<<<(NN + 3) / 4, 256, 0, stream>>>(B1, rowptr, ebuf, dinv, B2);
    k_mm<<<(NN + 63) / 64, 256, 0, stream>>>(B2, Wt[0], bl[0], dinv, B1, FIN, 1);
    // layers 2..5
    for (int l = 1; l < 5; ++l) {
        k_gather256<<<(NN + 3) / 4, 256, 0, stream>>>(B1, rowptr, ebuf, dinv, B2);
        k_mm<<<(NN + 63) / 64, 256, 0, stream>>>(B2, Wt[l], bl[l], dinv, B1, HD, (l < 4) ? 1 : 0);
    }

    k_poolout<<<NG, 256, 0, stream>>>(B1, gstart, Wout, bout, out);
}